// Round 1
// baseline (2493.807 us; speedup 1.0000x reference)
//
#include <hip/hip_runtime.h>
#include <math.h>

#define N_NODES 64512
#define DIN 84
#define DH 128
#define NPG 1008
#define BG 64
#define NSNAP 12
#define NSEG 84
#define NEDGE (N_NODES * 16)
#define ATT_SCALE 0.08838834764831845f  /* 1/sqrt(128) */

// ---------------------------------------------------------------------------
// GIN aggregation: agg[dst] += feat[src], direct atomics (round-1 baseline)
// ---------------------------------------------------------------------------
__global__ void scatter84(const float* __restrict__ x, const int* __restrict__ src,
                          const int* __restrict__ dst, float* __restrict__ agg) {
    int idx = blockIdx.x * blockDim.x + threadIdx.x;   // < NEDGE*84 = 86.7M
    if (idx >= NEDGE * DIN) return;
    int e = idx / DIN;
    int f = idx - e * DIN;
    atomicAdd(&agg[dst[e] * DIN + f], x[src[e] * DIN + f]);
}

__global__ void scatter128(const float* __restrict__ h, const int* __restrict__ src,
                           const int* __restrict__ dst, float* __restrict__ agg) {
    int idx = blockIdx.x * blockDim.x + threadIdx.x;   // < NEDGE*128 = 132M
    if (idx >= NEDGE * DH) return;
    int e = idx >> 7;
    int f = idx & 127;
    atomicAdd(&agg[dst[e] * DH + f], h[src[e] * DH + f]);
}

// ---------------------------------------------------------------------------
// h1 = (x + agg1) @ w1 + b1     (8 nodes per block, 128 threads)
// ---------------------------------------------------------------------------
__global__ void linear1(const float* __restrict__ x, const float* __restrict__ agg,
                        const float* __restrict__ w1, const float* __restrict__ b1,
                        float* __restrict__ h1) {
    __shared__ float xs[8][DIN];
    int n0 = blockIdx.x * 8;
    int tid = threadIdx.x;
    for (int i = tid; i < 8 * DIN; i += 128) {
        int r = i / DIN, f = i - r * DIN;
        int node = n0 + r;
        xs[r][f] = x[node * DIN + f] + agg[node * DIN + f];
    }
    __syncthreads();
    float acc[8];
    float bias = b1[tid];
#pragma unroll
    for (int r = 0; r < 8; r++) acc[r] = bias;
    for (int k = 0; k < DIN; k++) {
        float w = w1[k * DH + tid];
#pragma unroll
        for (int r = 0; r < 8; r++) acc[r] += xs[r][k] * w;
    }
#pragma unroll
    for (int r = 0; r < 8; r++) h1[(n0 + r) * DH + tid] = acc[r];
}

// ---------------------------------------------------------------------------
// h2 = (h1 + agg2) @ w2 + b2 + pe[node % 1008]
// ---------------------------------------------------------------------------
__global__ void linear2(const float* __restrict__ h1, const float* __restrict__ agg,
                        const float* __restrict__ w2, const float* __restrict__ b2,
                        const float* __restrict__ pe, float* __restrict__ h2) {
    __shared__ float hs[8][DH];
    int n0 = blockIdx.x * 8;
    int tid = threadIdx.x;
    for (int i = tid; i < 8 * DH; i += 128) {
        int r = i >> 7, f = i & 127;
        int node = n0 + r;
        hs[r][f] = h1[node * DH + f] + agg[node * DH + f];
    }
    __syncthreads();
    float acc[8];
    float bias = b2[tid];
#pragma unroll
    for (int r = 0; r < 8; r++) acc[r] = bias;
    for (int k = 0; k < DH; k++) {
        float w = w2[k * DH + tid];
#pragma unroll
        for (int r = 0; r < 8; r++) acc[r] += hs[r][k] * w;
    }
#pragma unroll
    for (int r = 0; r < 8; r++) {
        int node = n0 + r;
        int pos = node % NPG;
        h2[node * DH + tid] = acc[r] + pe[pos * DH + tid];
    }
}

// ---------------------------------------------------------------------------
// h2T[b][d][k] = h2[b*1008 + k][d]   (per-graph K transpose for coalesced QK^T)
// ---------------------------------------------------------------------------
__global__ void transposeK(const float* __restrict__ h2, float* __restrict__ h2T) {
    __shared__ float tile[32][33];
    int b = blockIdx.z;
    int k0 = blockIdx.x * 32;
    int d0 = blockIdx.y * 32;
    int tx = threadIdx.x;  // 32
    int ty = threadIdx.y;  // 8
    for (int i = ty; i < 32; i += 8) {
        int k = k0 + i;
        if (k < NPG) tile[i][tx] = h2[((size_t)b * NPG + k) * DH + d0 + tx];
    }
    __syncthreads();
    for (int i = ty; i < 32; i += 8) {
        int d = d0 + i;
        int k = k0 + tx;
        if (k < NPG) h2T[((size_t)b * DH + d) * NPG + k] = tile[tx][i];
    }
}

// ---------------------------------------------------------------------------
// Full self-attention per graph: 4 query rows per block, 128 threads.
// Scores read K^T (coalesced over keys); PV reads K (coalesced over dims).
// ---------------------------------------------------------------------------
#define GQ 4
__global__ __launch_bounds__(128) void attention(const float* __restrict__ h2,
                                                 const float* __restrict__ h2T,
                                                 float* __restrict__ ctx) {
    __shared__ float q[GQ][DH];
    __shared__ float sc[GQ][NPG];
    __shared__ float redbuf[2];
    int tid = threadIdx.x;
    int lane = tid & 63, wv = tid >> 6;
    const int bpg = NPG / GQ;  // 252
    int b = blockIdx.x / bpg;
    int q0 = (blockIdx.x - b * bpg) * GQ;
    const float* h2b = h2 + (size_t)b * NPG * DH;
    const float* h2Tb = h2T + (size_t)b * DH * NPG;

    for (int i = tid; i < GQ * DH; i += 128) {
        int r = i >> 7, d = i & 127;
        q[r][d] = h2b[(q0 + r) * DH + d];
    }
    __syncthreads();

    // scores: one thread per key, 8 chunks of 128 keys
    for (int kc = 0; kc < 8; kc++) {
        int k = kc * 128 + tid;
        if (k < NPG) {
            float a0 = 0.f, a1 = 0.f, a2 = 0.f, a3 = 0.f;
            for (int d = 0; d < DH; d++) {
                float kv = h2Tb[d * NPG + k];
                a0 += q[0][d] * kv;
                a1 += q[1][d] * kv;
                a2 += q[2][d] * kv;
                a3 += q[3][d] * kv;
            }
            sc[0][k] = a0 * ATT_SCALE;
            sc[1][k] = a1 * ATT_SCALE;
            sc[2][k] = a2 * ATT_SCALE;
            sc[3][k] = a3 * ATT_SCALE;
        }
    }
    __syncthreads();

    // softmax per query row
    float inv[GQ];
    for (int r = 0; r < GQ; r++) {
        float m = -1e30f;
        for (int k = tid; k < NPG; k += 128) m = fmaxf(m, sc[r][k]);
        for (int off = 32; off > 0; off >>= 1) m = fmaxf(m, __shfl_down(m, off));
        if (lane == 0) redbuf[wv] = m;
        __syncthreads();
        m = fmaxf(redbuf[0], redbuf[1]);
        __syncthreads();
        float s = 0.f;
        for (int k = tid; k < NPG; k += 128) {
            float p = __expf(sc[r][k] - m);
            sc[r][k] = p;
            s += p;
        }
        for (int off = 32; off > 0; off >>= 1) s += __shfl_down(s, off);
        if (lane == 0) redbuf[wv] = s;
        __syncthreads();
        inv[r] = 1.0f / (redbuf[0] + redbuf[1]);
        __syncthreads();
    }

    // ctx = P @ V : one thread per dim
    int d = tid;
    float a0 = 0.f, a1 = 0.f, a2 = 0.f, a3 = 0.f;
    for (int k = 0; k < NPG; k++) {
        float kv = h2b[k * DH + d];
        a0 += sc[0][k] * kv;
        a1 += sc[1][k] * kv;
        a2 += sc[2][k] * kv;
        a3 += sc[3][k] * kv;
    }
    ctx[((size_t)b * NPG + q0 + 0) * DH + d] = a0 * inv[0];
    ctx[((size_t)b * NPG + q0 + 1) * DH + d] = a1 * inv[1];
    ctx[((size_t)b * NPG + q0 + 2) * DH + d] = a2 * inv[2];
    ctx[((size_t)b * NPG + q0 + 3) * DH + d] = a3 * inv[3];
}

// ---------------------------------------------------------------------------
// Segmented max/mean pooling -> feat[B,12,512]
// ---------------------------------------------------------------------------
__global__ void pooling(const float* __restrict__ h1, const float* __restrict__ ctx,
                        float* __restrict__ feat) {
    int bs = blockIdx.x;   // b*12 + s, 0..767
    int d = threadIdx.x;   // 128
    int base = bs * NSEG;  // global node offset of segment
    float mx1 = -1e30f, sm1 = 0.f, mx2 = -1e30f, sm2 = 0.f;
    for (int n = 0; n < NSEG; n++) {
        float v1 = h1[(base + n) * DH + d];
        mx1 = fmaxf(mx1, v1);
        sm1 += v1;
        float v2 = ctx[(base + n) * DH + d];
        mx2 = fmaxf(mx2, v2);
        sm2 += v2;
    }
    const float invs = 1.0f / NSEG;
    feat[bs * 512 + d] = mx1;
    feat[bs * 512 + 128 + d] = sm1 * invs;
    feat[bs * 512 + 256 + d] = mx2;
    feat[bs * 512 + 384 + d] = sm2 * invs;
}

// ---------------------------------------------------------------------------
// y1raw[64,512] = feat[64,6144] @ wf1 + bf1   (4 rows per block)
// ---------------------------------------------------------------------------
__global__ void mlp1(const float* __restrict__ feat, const float* __restrict__ wf1,
                     const float* __restrict__ bf1, float* __restrict__ y1raw) {
    int col = blockIdx.x * 256 + threadIdx.x;  // 0..511
    int r0 = blockIdx.y * 4;                   // 0..60
    float bias = bf1[col];
    float a0 = bias, a1 = bias, a2 = bias, a3 = bias;
    const float* f0 = feat + (size_t)r0 * 6144;
    for (int k = 0; k < 6144; k++) {
        float w = wf1[k * 512 + col];
        a0 += f0[k] * w;
        a1 += f0[6144 + k] * w;
        a2 += f0[12288 + k] * w;
        a3 += f0[18432 + k] * w;
    }
    y1raw[(r0 + 0) * 512 + col] = a0;
    y1raw[(r0 + 1) * 512 + col] = a1;
    y1raw[(r0 + 2) * 512 + col] = a2;
    y1raw[(r0 + 3) * 512 + col] = a3;
}

// ---------------------------------------------------------------------------
// out = BN(silu(raw)) : one block per column, 64 threads = 64 batch rows
// ---------------------------------------------------------------------------
__global__ void bn_silu(const float* __restrict__ raw, const float* __restrict__ g,
                        const float* __restrict__ be, float* __restrict__ out, int C) {
    int j = blockIdx.x;
    int b = threadIdx.x;  // 64 = one wave
    float v = raw[b * C + j];
    float h = v / (1.0f + __expf(-v));
    float s = h, s2 = h * h;
    for (int off = 1; off < 64; off <<= 1) {
        s += __shfl_xor(s, off);
        s2 += __shfl_xor(s2, off);
    }
    float mu = s * (1.0f / 64.0f);
    float var = s2 * (1.0f / 64.0f) - mu * mu;
    float scale = rsqrtf(var + 1e-5f) * g[j];
    out[b * C + j] = (h - mu) * scale + be[j];
}

__global__ void mlp2(const float* __restrict__ y1, const float* __restrict__ wf2,
                     const float* __restrict__ bf2, float* __restrict__ y2raw) {
    int j = blockIdx.x;   // 32
    int b = threadIdx.x;  // 64
    float acc = bf2[j];
    for (int k = 0; k < 512; k++) acc += y1[b * 512 + k] * wf2[k * 32 + j];
    y2raw[b * 32 + j] = acc;
}

__global__ void mlp3(const float* __restrict__ y2, const float* __restrict__ wf3,
                     const float* __restrict__ bf3, float* __restrict__ out) {
    int b = threadIdx.x;  // 64
    float l0 = bf3[0], l1 = bf3[1];
    for (int k = 0; k < 32; k++) {
        float v = y2[b * 32 + k];
        l0 += v * wf3[k * 2 + 0];
        l1 += v * wf3[k * 2 + 1];
    }
    float m = fmaxf(l0, l1);
    float e0 = __expf(l0 - m), e1 = __expf(l1 - m);
    float inv = 1.0f / (e0 + e1);
    out[b * 2 + 0] = e0 * inv;
    out[b * 2 + 1] = e1 * inv;
}

// ---------------------------------------------------------------------------
extern "C" void kernel_launch(void* const* d_in, const int* in_sizes, int n_in,
                              void* d_out, int out_size, void* d_ws, size_t ws_size,
                              hipStream_t stream) {
    const float* x   = (const float*)d_in[0];
    const int*   ei  = (const int*)d_in[1];
    const float* w1  = (const float*)d_in[2];
    const float* b1  = (const float*)d_in[3];
    const float* w2  = (const float*)d_in[4];
    const float* b2  = (const float*)d_in[5];
    const float* pe  = (const float*)d_in[6];
    const float* wf1 = (const float*)d_in[7];
    const float* bf1 = (const float*)d_in[8];
    const float* g1  = (const float*)d_in[9];
    const float* be1 = (const float*)d_in[10];
    const float* wf2 = (const float*)d_in[11];
    const float* bf2 = (const float*)d_in[12];
    const float* g2  = (const float*)d_in[13];
    const float* be2 = (const float*)d_in[14];
    const float* wf3 = (const float*)d_in[15];
    const float* bf3 = (const float*)d_in[16];
    float* out = (float*)d_out;

    const int* srcp = ei;
    const int* dstp = ei + NEDGE;

    // workspace layout (floats)
    float* ws = (float*)d_ws;
    size_t off = 0;
    float* agg1 = ws + off; off += (size_t)N_NODES * DIN;  // zeroed
    float* agg2 = ws + off; off += (size_t)N_NODES * DH;   // zeroed
    float* h1   = ws + off; off += (size_t)N_NODES * DH;
    float* h2   = ws + off; off += (size_t)N_NODES * DH;
    float* h2T  = ws + off; off += (size_t)N_NODES * DH;
    float* y1raw = ws + off; off += 64 * 512;
    float* y1    = ws + off; off += 64 * 512;
    float* y2raw = ws + off; off += 64 * 32;
    float* y2    = ws + off; off += 64 * 32;
    float* ctxb = agg2;  // agg2 dead after linear2
    float* feat = agg1;  // agg1 dead after linear1 (needs 393K floats < 5.4M)

    // zero the scatter accumulators (agg1, agg2 are contiguous at ws start)
    hipMemsetAsync(d_ws, 0,
                   (size_t)(N_NODES * DIN + N_NODES * DH) * sizeof(float), stream);

    {
        int total = NEDGE * DIN;  // 86,704,128
        scatter84<<<(total + 255) / 256, 256, 0, stream>>>(x, srcp, dstp, agg1);
    }
    linear1<<<N_NODES / 8, 128, 0, stream>>>(x, agg1, w1, b1, h1);
    {
        int total = NEDGE * DH;   // 132,120,576
        scatter128<<<(total + 255) / 256, 256, 0, stream>>>(h1, srcp, dstp, agg2);
    }
    linear2<<<N_NODES / 8, 128, 0, stream>>>(h1, agg2, w2, b2, pe, h2);
    transposeK<<<dim3(32, 4, BG), dim3(32, 8), 0, stream>>>(h2, h2T);
    attention<<<BG * (NPG / GQ), 128, 0, stream>>>(h2, h2T, ctxb);
    pooling<<<BG * NSNAP, 128, 0, stream>>>(h1, ctxb, feat);
    mlp1<<<dim3(2, 16), 256, 0, stream>>>(feat, wf1, bf1, y1raw);
    bn_silu<<<512, 64, 0, stream>>>(y1raw, g1, be1, y1, 512);
    mlp2<<<32, 64, 0, stream>>>(y1, wf2, bf2, y2raw);
    bn_silu<<<32, 64, 0, stream>>>(y2raw, g2, be2, y2, 32);
    mlp3<<<1, 64, 0, stream>>>(y2, wf3, bf3, out);
}

// Round 2
// 1539.548 us; speedup vs baseline: 1.6198x; 1.6198x over previous
//
#include <hip/hip_runtime.h>
#include <math.h>

#define N_NODES 64512
#define DIN 84
#define DH 128
#define NPG 1008
#define BG 64
#define NSNAP 12
#define NSEG 84
#define NEDGE (N_NODES * 16)
#define ATT_SCALE 0.08838834764831845f /* 1/sqrt(128) */

typedef __bf16 bf16_t;
typedef __bf16 bf16x8 __attribute__((ext_vector_type(8)));
typedef float f32x4 __attribute__((ext_vector_type(4)));

// ---------------------------------------------------------------------------
// GIN aggregation: agg[dst] += feat[src], direct atomics (still baseline)
// ---------------------------------------------------------------------------
__global__ void scatter84(const float* __restrict__ x, const int* __restrict__ src,
                          const int* __restrict__ dst, float* __restrict__ agg) {
    int idx = blockIdx.x * blockDim.x + threadIdx.x;
    if (idx >= NEDGE * DIN) return;
    int e = idx / DIN;
    int f = idx - e * DIN;
    atomicAdd(&agg[dst[e] * DIN + f], x[src[e] * DIN + f]);
}

__global__ void scatter128(const float* __restrict__ h, const int* __restrict__ src,
                           const int* __restrict__ dst, float* __restrict__ agg) {
    int idx = blockIdx.x * blockDim.x + threadIdx.x;
    if (idx >= NEDGE * DH) return;
    int e = idx >> 7;
    int f = idx & 127;
    atomicAdd(&agg[dst[e] * DH + f], h[src[e] * DH + f]);
}

// ---------------------------------------------------------------------------
// h1 = (x + agg1) @ w1 + b1
// ---------------------------------------------------------------------------
__global__ void linear1(const float* __restrict__ x, const float* __restrict__ agg,
                        const float* __restrict__ w1, const float* __restrict__ b1,
                        float* __restrict__ h1) {
    __shared__ float xs[8][DIN];
    int n0 = blockIdx.x * 8;
    int tid = threadIdx.x;
    for (int i = tid; i < 8 * DIN; i += 128) {
        int r = i / DIN, f = i - r * DIN;
        int node = n0 + r;
        xs[r][f] = x[node * DIN + f] + agg[node * DIN + f];
    }
    __syncthreads();
    float acc[8];
    float bias = b1[tid];
#pragma unroll
    for (int r = 0; r < 8; r++) acc[r] = bias;
    for (int k = 0; k < DIN; k++) {
        float w = w1[k * DH + tid];
#pragma unroll
        for (int r = 0; r < 8; r++) acc[r] += xs[r][k] * w;
    }
#pragma unroll
    for (int r = 0; r < 8; r++) h1[(n0 + r) * DH + tid] = acc[r];
}

// ---------------------------------------------------------------------------
// h2bf = bf16( (h1 + agg2) @ w2 + b2 + pe[node % 1008] )
// ---------------------------------------------------------------------------
__global__ void linear2(const float* __restrict__ h1, const float* __restrict__ agg,
                        const float* __restrict__ w2, const float* __restrict__ b2,
                        const float* __restrict__ pe, bf16_t* __restrict__ h2bf) {
    __shared__ float hs[8][DH];
    int n0 = blockIdx.x * 8;
    int tid = threadIdx.x;
    for (int i = tid; i < 8 * DH; i += 128) {
        int r = i >> 7, f = i & 127;
        int node = n0 + r;
        hs[r][f] = h1[node * DH + f] + agg[node * DH + f];
    }
    __syncthreads();
    float acc[8];
    float bias = b2[tid];
#pragma unroll
    for (int r = 0; r < 8; r++) acc[r] = bias;
    for (int k = 0; k < DH; k++) {
        float w = w2[k * DH + tid];
#pragma unroll
        for (int r = 0; r < 8; r++) acc[r] += hs[r][k] * w;
    }
#pragma unroll
    for (int r = 0; r < 8; r++) {
        int node = n0 + r;
        int pos = node % NPG;
        h2bf[(size_t)node * DH + tid] = (bf16_t)(acc[r] + pe[pos * DH + tid]);
    }
}

// ---------------------------------------------------------------------------
// h2T[b][d][k] = h2bf[b*1008 + k][d]   (bf16 transposed copy for PV B-operand)
// ---------------------------------------------------------------------------
__global__ void transposeK(const bf16_t* __restrict__ h2bf, bf16_t* __restrict__ h2T) {
    __shared__ bf16_t tile[32][34];
    int b = blockIdx.z;
    int k0 = blockIdx.x * 32;
    int d0 = blockIdx.y * 32;
    int tx = threadIdx.x;  // 32
    int ty = threadIdx.y;  // 8
    for (int i = ty; i < 32; i += 8) {
        int k = k0 + i;
        tile[i][tx] = (k < NPG) ? h2bf[((size_t)b * NPG + k) * DH + d0 + tx] : (bf16_t)0.0f;
    }
    __syncthreads();
    for (int i = ty; i < 32; i += 8) {
        int k = k0 + tx;
        if (k < NPG) h2T[((size_t)b * DH + d0 + i) * NPG + k] = tile[tx][i];
    }
}

// ---------------------------------------------------------------------------
// Flash-style MFMA attention. Block = 256 threads (4 waves) = 64 Q rows of one
// graph. K-loop over 16 tiles of 64 keys (padded 1008->1024, masked scores).
//   Qs/Ks row-major [row][dim]  -> A / B fragments for QK^T (k = dim)
//   Kt row-major [dim][key]     -> B fragments for PV       (k = key)
//   Ps [qrow][key]              -> P C-layout -> A-layout round trip
// ---------------------------------------------------------------------------
#define QTILE 64
#define KTILE 64
#define QK_PITCH 136  /* bf16 units, 128+8 */
#define KT_PITCH 72   /* bf16 units, 64+8  */

__global__ __launch_bounds__(256) void attn_mfma(const bf16_t* __restrict__ h2bf,
                                                 const bf16_t* __restrict__ h2T,
                                                 float* __restrict__ ctx) {
    __shared__ bf16_t Qs[QTILE][QK_PITCH];
    __shared__ bf16_t Ks[KTILE][QK_PITCH];
    __shared__ bf16_t Kt[DH][KT_PITCH];
    __shared__ bf16_t Ps[QTILE][KT_PITCH];

    int tid = threadIdx.x;
    int wv = tid >> 6, lane = tid & 63;
    int l15 = lane & 15, quad = lane >> 4;
    int b = blockIdx.x >> 4;
    int qt = blockIdx.x & 15;
    const bf16_t* hb = h2bf + (size_t)b * NPG * DH;
    const bf16_t* hbT = h2T + (size_t)b * DH * NPG;

    // ---- load Q tile (64 rows x 128 dims) ----
    for (int c = tid; c < QTILE * 16; c += 256) {
        int row = c >> 4, seg = c & 15;
        int qrow = qt * QTILE + row;
        uint4 v = {0u, 0u, 0u, 0u};
        if (qrow < NPG) v = *(const uint4*)(hb + (size_t)qrow * DH + seg * 8);
        *(uint4*)&Qs[row][seg * 8] = v;
    }
    __syncthreads();

    // ---- preload Q A-fragments (4 k-blocks of 32 dims) ----
    bf16x8 aQ[4];
    int qr = wv * 16 + l15;
#pragma unroll
    for (int kb = 0; kb < 4; kb++)
        aQ[kb] = *(const bf16x8*)&Qs[qr][kb * 32 + quad * 8];

    // ---- online-softmax state ----
    float m_i[4], l_i[4];
    f32x4 O[8];
#pragma unroll
    for (int r = 0; r < 4; r++) { m_i[r] = -1e30f; l_i[r] = 0.0f; }
#pragma unroll
    for (int t = 0; t < 8; t++) O[t] = (f32x4){0.f, 0.f, 0.f, 0.f};

    for (int kt = 0; kt < 16; kt++) {
        __syncthreads();  // previous iteration's LDS reads complete
        // ---- stage K tile: Ks[key][dim] and Kt[dim][key] ----
        for (int c = tid; c < KTILE * 16; c += 256) {
            int row = c >> 4, seg = c & 15;
            int key = kt * KTILE + row;
            uint4 v = {0u, 0u, 0u, 0u};
            if (key < NPG) v = *(const uint4*)(hb + (size_t)key * DH + seg * 8);
            *(uint4*)&Ks[row][seg * 8] = v;
        }
        for (int c = tid; c < DH * 8; c += 256) {
            int dim = c >> 3, kc = c & 7;
            int key0 = kt * KTILE + kc * 8;
            uint4 v = {0u, 0u, 0u, 0u};
            if (key0 < NPG) v = *(const uint4*)(hbT + (size_t)dim * NPG + key0);
            *(uint4*)&Kt[dim][kc * 8] = v;
        }
        __syncthreads();

        // ---- S = Q K^T for this wave's 16 rows x 64 keys ----
        f32x4 S[4];
#pragma unroll
        for (int nt = 0; nt < 4; nt++) {
            f32x4 acc = {0.f, 0.f, 0.f, 0.f};
#pragma unroll
            for (int kb = 0; kb < 4; kb++) {
                bf16x8 bK = *(const bf16x8*)&Ks[nt * 16 + l15][kb * 32 + quad * 8];
                acc = __builtin_amdgcn_mfma_f32_16x16x32_bf16(aQ[kb], bK, acc, 0, 0, 0);
            }
            S[nt] = acc;
        }

        // ---- scale + mask ----
        float sm[4][4];
#pragma unroll
        for (int nt = 0; nt < 4; nt++) {
            int key = kt * KTILE + nt * 16 + l15;
            bool valid = key < NPG;
#pragma unroll
            for (int r = 0; r < 4; r++)
                sm[nt][r] = valid ? S[nt][r] * ATT_SCALE : -1e30f;
        }

        // ---- row max (across 4 nt tiles, then across the 16 lanes of a row) ----
        float tmax[4];
#pragma unroll
        for (int r = 0; r < 4; r++)
            tmax[r] = fmaxf(fmaxf(sm[0][r], sm[1][r]), fmaxf(sm[2][r], sm[3][r]));
#pragma unroll
        for (int off = 1; off < 16; off <<= 1)
#pragma unroll
            for (int r = 0; r < 4; r++) tmax[r] = fmaxf(tmax[r], __shfl_xor(tmax[r], off));

        float alpha[4], newm[4];
#pragma unroll
        for (int r = 0; r < 4; r++) {
            newm[r] = fmaxf(m_i[r], tmax[r]);
            alpha[r] = __expf(m_i[r] - newm[r]);
            m_i[r] = newm[r];
        }

        // ---- P = exp(S - m), row sums ----
        float ps[4][4];
        float rsum[4] = {0.f, 0.f, 0.f, 0.f};
#pragma unroll
        for (int nt = 0; nt < 4; nt++)
#pragma unroll
            for (int r = 0; r < 4; r++) {
                float p = __expf(sm[nt][r] - newm[r]);
                ps[nt][r] = p;
                rsum[r] += p;
            }
#pragma unroll
        for (int off = 1; off < 16; off <<= 1)
#pragma unroll
            for (int r = 0; r < 4; r++) rsum[r] += __shfl_xor(rsum[r], off);
#pragma unroll
        for (int r = 0; r < 4; r++) l_i[r] = l_i[r] * alpha[r] + rsum[r];

        // ---- rescale O ----
#pragma unroll
        for (int t = 0; t < 8; t++)
#pragma unroll
            for (int r = 0; r < 4; r++) O[t][r] *= alpha[r];

        // ---- P: C-layout -> LDS (bf16) ----
#pragma unroll
        for (int nt = 0; nt < 4; nt++)
#pragma unroll
            for (int r = 0; r < 4; r++)
                Ps[wv * 16 + quad * 4 + r][nt * 16 + l15] = (bf16_t)ps[nt][r];

        // ---- O += P V ----
#pragma unroll
        for (int kb2 = 0; kb2 < 2; kb2++) {
            bf16x8 aP = *(const bf16x8*)&Ps[wv * 16 + l15][kb2 * 32 + quad * 8];
#pragma unroll
            for (int t = 0; t < 8; t++) {
                bf16x8 bV = *(const bf16x8*)&Kt[t * 16 + l15][kb2 * 32 + quad * 8];
                O[t] = __builtin_amdgcn_mfma_f32_16x16x32_bf16(aP, bV, O[t], 0, 0, 0);
            }
        }
    }

    // ---- epilogue: O / l ----
    float invl[4];
#pragma unroll
    for (int r = 0; r < 4; r++) invl[r] = 1.0f / l_i[r];
    float* cb = ctx + (size_t)b * NPG * DH;
#pragma unroll
    for (int t = 0; t < 8; t++)
#pragma unroll
        for (int r = 0; r < 4; r++) {
            int qrow = qt * QTILE + wv * 16 + quad * 4 + r;
            if (qrow < NPG) cb[(size_t)qrow * DH + t * 16 + l15] = O[t][r] * invl[r];
        }
}

// ---------------------------------------------------------------------------
// Segmented max/mean pooling -> feat[B,12,512]
// ---------------------------------------------------------------------------
__global__ void pooling(const float* __restrict__ h1, const float* __restrict__ ctx,
                        float* __restrict__ feat) {
    int bs = blockIdx.x;
    int d = threadIdx.x;
    int base = bs * NSEG;
    float mx1 = -1e30f, sm1 = 0.f, mx2 = -1e30f, sm2 = 0.f;
    for (int n = 0; n < NSEG; n++) {
        float v1 = h1[(base + n) * DH + d];
        mx1 = fmaxf(mx1, v1);
        sm1 += v1;
        float v2 = ctx[(base + n) * DH + d];
        mx2 = fmaxf(mx2, v2);
        sm2 += v2;
    }
    const float invs = 1.0f / NSEG;
    feat[bs * 512 + d] = mx1;
    feat[bs * 512 + 128 + d] = sm1 * invs;
    feat[bs * 512 + 256 + d] = mx2;
    feat[bs * 512 + 384 + d] = sm2 * invs;
}

// ---------------------------------------------------------------------------
// MLP head (unchanged)
// ---------------------------------------------------------------------------
__global__ void mlp1(const float* __restrict__ feat, const float* __restrict__ wf1,
                     const float* __restrict__ bf1, float* __restrict__ y1raw) {
    int col = blockIdx.x * 256 + threadIdx.x;
    int r0 = blockIdx.y * 4;
    float bias = bf1[col];
    float a0 = bias, a1 = bias, a2 = bias, a3 = bias;
    const float* f0 = feat + (size_t)r0 * 6144;
    for (int k = 0; k < 6144; k++) {
        float w = wf1[k * 512 + col];
        a0 += f0[k] * w;
        a1 += f0[6144 + k] * w;
        a2 += f0[12288 + k] * w;
        a3 += f0[18432 + k] * w;
    }
    y1raw[(r0 + 0) * 512 + col] = a0;
    y1raw[(r0 + 1) * 512 + col] = a1;
    y1raw[(r0 + 2) * 512 + col] = a2;
    y1raw[(r0 + 3) * 512 + col] = a3;
}

__global__ void bn_silu(const float* __restrict__ raw, const float* __restrict__ g,
                        const float* __restrict__ be, float* __restrict__ out, int C) {
    int j = blockIdx.x;
    int b = threadIdx.x;
    float v = raw[b * C + j];
    float h = v / (1.0f + __expf(-v));
    float s = h, s2 = h * h;
    for (int off = 1; off < 64; off <<= 1) {
        s += __shfl_xor(s, off);
        s2 += __shfl_xor(s2, off);
    }
    float mu = s * (1.0f / 64.0f);
    float var = s2 * (1.0f / 64.0f) - mu * mu;
    float scale = rsqrtf(var + 1e-5f) * g[j];
    out[b * C + j] = (h - mu) * scale + be[j];
}

__global__ void mlp2(const float* __restrict__ y1, const float* __restrict__ wf2,
                     const float* __restrict__ bf2, float* __restrict__ y2raw) {
    int j = blockIdx.x;
    int b = threadIdx.x;
    float acc = bf2[j];
    for (int k = 0; k < 512; k++) acc += y1[b * 512 + k] * wf2[k * 32 + j];
    y2raw[b * 32 + j] = acc;
}

__global__ void mlp3(const float* __restrict__ y2, const float* __restrict__ wf3,
                     const float* __restrict__ bf3, float* __restrict__ out) {
    int b = threadIdx.x;
    float l0 = bf3[0], l1 = bf3[1];
    for (int k = 0; k < 32; k++) {
        float v = y2[b * 32 + k];
        l0 += v * wf3[k * 2 + 0];
        l1 += v * wf3[k * 2 + 1];
    }
    float m = fmaxf(l0, l1);
    float e0 = __expf(l0 - m), e1 = __expf(l1 - m);
    float inv = 1.0f / (e0 + e1);
    out[b * 2 + 0] = e0 * inv;
    out[b * 2 + 1] = e1 * inv;
}

// ---------------------------------------------------------------------------
extern "C" void kernel_launch(void* const* d_in, const int* in_sizes, int n_in,
                              void* d_out, int out_size, void* d_ws, size_t ws_size,
                              hipStream_t stream) {
    const float* x   = (const float*)d_in[0];
    const int*   ei  = (const int*)d_in[1];
    const float* w1  = (const float*)d_in[2];
    const float* b1  = (const float*)d_in[3];
    const float* w2  = (const float*)d_in[4];
    const float* b2  = (const float*)d_in[5];
    const float* pe  = (const float*)d_in[6];
    const float* wf1 = (const float*)d_in[7];
    const float* bf1 = (const float*)d_in[8];
    const float* g1  = (const float*)d_in[9];
    const float* be1 = (const float*)d_in[10];
    const float* wf2 = (const float*)d_in[11];
    const float* bf2 = (const float*)d_in[12];
    const float* g2  = (const float*)d_in[13];
    const float* be2 = (const float*)d_in[14];
    const float* wf3 = (const float*)d_in[15];
    const float* bf3 = (const float*)d_in[16];
    float* out = (float*)d_out;

    const int* srcp = ei;
    const int* dstp = ei + NEDGE;

    // workspace layout (float units; bf16 buffers counted as half-floats)
    float* ws = (float*)d_ws;
    size_t off = 0;
    float* agg1 = ws + off; off += (size_t)N_NODES * DIN;   // zeroed
    float* agg2 = ws + off; off += (size_t)N_NODES * DH;    // zeroed
    float* h1   = ws + off; off += (size_t)N_NODES * DH;
    bf16_t* h2bf = (bf16_t*)(ws + off); off += (size_t)N_NODES * DH / 2;
    bf16_t* h2T  = (bf16_t*)(ws + off); off += (size_t)N_NODES * DH / 2;
    float* y1raw = ws + off; off += 64 * 512;
    float* y1    = ws + off; off += 64 * 512;
    float* y2raw = ws + off; off += 64 * 32;
    float* y2    = ws + off; off += 64 * 32;
    float* ctxb = agg2;  // agg2 dead after linear2
    float* feat = agg1;  // agg1 dead after linear1

    hipMemsetAsync(d_ws, 0,
                   (size_t)(N_NODES * DIN + N_NODES * DH) * sizeof(float), stream);

    {
        int total = NEDGE * DIN;
        scatter84<<<(total + 255) / 256, 256, 0, stream>>>(x, srcp, dstp, agg1);
    }
    linear1<<<N_NODES / 8, 128, 0, stream>>>(x, agg1, w1, b1, h1);
    {
        int total = NEDGE * DH;
        scatter128<<<(total + 255) / 256, 256, 0, stream>>>(h1, srcp, dstp, agg2);
    }
    linear2<<<N_NODES / 8, 128, 0, stream>>>(h1, agg2, w2, b2, pe, h2bf);
    transposeK<<<dim3(32, 4, BG), dim3(32, 8), 0, stream>>>(h2bf, h2T);
    attn_mfma<<<BG * 16, 256, 0, stream>>>(h2bf, h2T, ctxb);
    pooling<<<BG * NSNAP, 128, 0, stream>>>(h1, ctxb, feat);
    mlp1<<<dim3(2, 16), 256, 0, stream>>>(feat, wf1, bf1, y1raw);
    bn_silu<<<512, 64, 0, stream>>>(y1raw, g1, be1, y1, 512);
    mlp2<<<32, 64, 0, stream>>>(y1, wf2, bf2, y2raw);
    bn_silu<<<32, 64, 0, stream>>>(y2raw, g2, be2, y2, 32);
    mlp3<<<1, 64, 0, stream>>>(y2, wf3, bf3, out);
}

// Round 3
// 1043.386 us; speedup vs baseline: 2.3901x; 1.4755x over previous
//
#include <hip/hip_runtime.h>
#include <math.h>

#define N_NODES 64512
#define DIN 84
#define DH 128
#define NPG 1008
#define BG 64
#define NSNAP 12
#define NSEG 84
#define NEDGE (N_NODES * 16)
#define ATT_SCALE 0.08838834764831845f /* 1/sqrt(128) */

typedef __bf16 bf16_t;
typedef __bf16 bf16x8 __attribute__((ext_vector_type(8)));
typedef float f32x4 __attribute__((ext_vector_type(4)));

// ---------------------------------------------------------------------------
// CSR build: degree count -> exclusive scan -> bucket fill
// ---------------------------------------------------------------------------
__global__ void count_deg(const int* __restrict__ dst, int* __restrict__ deg) {
    int e = blockIdx.x * blockDim.x + threadIdx.x;
    if (e < NEDGE) atomicAdd(&deg[dst[e]], 1);
}

// one block, 1024 threads, 63 elements each (1024*63 == 64512)
__global__ __launch_bounds__(1024) void scan_deg(const int* __restrict__ deg,
                                                 int* __restrict__ off) {
    __shared__ int ssum[1024];
    int tid = threadIdx.x;
    int base = tid * 63;
    int s = 0;
#pragma unroll 7
    for (int j = 0; j < 63; j++) s += deg[base + j];
    ssum[tid] = s;
    __syncthreads();
    for (int d = 1; d < 1024; d <<= 1) {
        int v = (tid >= d) ? ssum[tid - d] : 0;
        __syncthreads();
        ssum[tid] += v;
        __syncthreads();
    }
    int run = (tid == 0) ? 0 : ssum[tid - 1];
#pragma unroll 7
    for (int j = 0; j < 63; j++) {
        off[base + j] = run;
        run += deg[base + j];
    }
    if (tid == 1023) off[N_NODES] = run;
}

__global__ void fill_csr(const int* __restrict__ src, const int* __restrict__ dst,
                         int* __restrict__ cursor, int* __restrict__ eidx) {
    int e = blockIdx.x * blockDim.x + threadIdx.x;
    if (e < NEDGE) {
        int p = atomicAdd(&cursor[dst[e]], 1);
        eidx[p] = src[e];
    }
}

// ---------------------------------------------------------------------------
// Gather aggregation (replaces atomic scatter): agg[i] = sum_j x[eidx[j]]
// ---------------------------------------------------------------------------
__global__ __launch_bounds__(256) void gather84(const float* __restrict__ x,
                                                const int* __restrict__ off,
                                                const int* __restrict__ eidx,
                                                float* __restrict__ agg) {
    int node = blockIdx.x * 4 + (threadIdx.x >> 6);
    int lane = threadIdx.x & 63;
    int s = off[node], e = off[node + 1];
    for (int f = lane; f < DIN; f += 64) {
        float acc = 0.f;
        int i = s;
        for (; i + 4 <= e; i += 4) {
            int i0 = eidx[i], i1 = eidx[i + 1], i2 = eidx[i + 2], i3 = eidx[i + 3];
            acc += x[(size_t)i0 * DIN + f] + x[(size_t)i1 * DIN + f] +
                   x[(size_t)i2 * DIN + f] + x[(size_t)i3 * DIN + f];
        }
        for (; i < e; i++) acc += x[(size_t)eidx[i] * DIN + f];
        agg[(size_t)node * DIN + f] = acc;
    }
}

__global__ __launch_bounds__(256) void gather128(const float* __restrict__ h,
                                                 const int* __restrict__ off,
                                                 const int* __restrict__ eidx,
                                                 float* __restrict__ agg) {
    int node = blockIdx.x * 2 + (threadIdx.x >> 7);
    int f = threadIdx.x & 127;
    int s = off[node], e = off[node + 1];
    float acc = 0.f;
    int i = s;
    for (; i + 4 <= e; i += 4) {
        int i0 = eidx[i], i1 = eidx[i + 1], i2 = eidx[i + 2], i3 = eidx[i + 3];
        acc += h[(size_t)i0 * DH + f] + h[(size_t)i1 * DH + f] +
               h[(size_t)i2 * DH + f] + h[(size_t)i3 * DH + f];
    }
    for (; i < e; i++) acc += h[(size_t)eidx[i] * DH + f];
    agg[(size_t)node * DH + f] = acc;
}

// ---------------------------------------------------------------------------
// h1 = (x + agg1) @ w1 + b1
// ---------------------------------------------------------------------------
__global__ void linear1(const float* __restrict__ x, const float* __restrict__ agg,
                        const float* __restrict__ w1, const float* __restrict__ b1,
                        float* __restrict__ h1) {
    __shared__ float xs[8][DIN];
    int n0 = blockIdx.x * 8;
    int tid = threadIdx.x;
    for (int i = tid; i < 8 * DIN; i += 128) {
        int r = i / DIN, f = i - r * DIN;
        int node = n0 + r;
        xs[r][f] = x[node * DIN + f] + agg[node * DIN + f];
    }
    __syncthreads();
    float acc[8];
    float bias = b1[tid];
#pragma unroll
    for (int r = 0; r < 8; r++) acc[r] = bias;
    for (int k = 0; k < DIN; k++) {
        float w = w1[k * DH + tid];
#pragma unroll
        for (int r = 0; r < 8; r++) acc[r] += xs[r][k] * w;
    }
#pragma unroll
    for (int r = 0; r < 8; r++) h1[(n0 + r) * DH + tid] = acc[r];
}

// ---------------------------------------------------------------------------
// h2bf = bf16( (h1 + agg2) @ w2 + b2 + pe[node % 1008] )
// ---------------------------------------------------------------------------
__global__ void linear2(const float* __restrict__ h1, const float* __restrict__ agg,
                        const float* __restrict__ w2, const float* __restrict__ b2,
                        const float* __restrict__ pe, bf16_t* __restrict__ h2bf) {
    __shared__ float hs[8][DH];
    int n0 = blockIdx.x * 8;
    int tid = threadIdx.x;
    for (int i = tid; i < 8 * DH; i += 128) {
        int r = i >> 7, f = i & 127;
        int node = n0 + r;
        hs[r][f] = h1[node * DH + f] + agg[node * DH + f];
    }
    __syncthreads();
    float acc[8];
    float bias = b2[tid];
#pragma unroll
    for (int r = 0; r < 8; r++) acc[r] = bias;
    for (int k = 0; k < DH; k++) {
        float w = w2[k * DH + tid];
#pragma unroll
        for (int r = 0; r < 8; r++) acc[r] += hs[r][k] * w;
    }
#pragma unroll
    for (int r = 0; r < 8; r++) {
        int node = n0 + r;
        int pos = node % NPG;
        h2bf[(size_t)node * DH + tid] = (bf16_t)(acc[r] + pe[pos * DH + tid]);
    }
}

// ---------------------------------------------------------------------------
// h2T[b][d][k] = h2bf[b*1008 + k][d]
// ---------------------------------------------------------------------------
__global__ void transposeK(const bf16_t* __restrict__ h2bf, bf16_t* __restrict__ h2T) {
    __shared__ bf16_t tile[32][34];
    int b = blockIdx.z;
    int k0 = blockIdx.x * 32;
    int d0 = blockIdx.y * 32;
    int tx = threadIdx.x;
    int ty = threadIdx.y;
    for (int i = ty; i < 32; i += 8) {
        int k = k0 + i;
        tile[i][tx] = (k < NPG) ? h2bf[((size_t)b * NPG + k) * DH + d0 + tx] : (bf16_t)0.0f;
    }
    __syncthreads();
    for (int i = ty; i < 32; i += 8) {
        int k = k0 + tx;
        if (k < NPG) h2T[((size_t)b * DH + d0 + i) * NPG + k] = tile[tx][i];
    }
}

// ---------------------------------------------------------------------------
// Flash-style MFMA attention (unchanged from round 2)
// ---------------------------------------------------------------------------
#define QTILE 64
#define KTILE 64
#define QK_PITCH 136
#define KT_PITCH 72

__global__ __launch_bounds__(256) void attn_mfma(const bf16_t* __restrict__ h2bf,
                                                 const bf16_t* __restrict__ h2T,
                                                 float* __restrict__ ctx) {
    __shared__ bf16_t Qs[QTILE][QK_PITCH];
    __shared__ bf16_t Ks[KTILE][QK_PITCH];
    __shared__ bf16_t Kt[DH][KT_PITCH];
    __shared__ bf16_t Ps[QTILE][KT_PITCH];

    int tid = threadIdx.x;
    int wv = tid >> 6, lane = tid & 63;
    int l15 = lane & 15, quad = lane >> 4;
    int b = blockIdx.x >> 4;
    int qt = blockIdx.x & 15;
    const bf16_t* hb = h2bf + (size_t)b * NPG * DH;
    const bf16_t* hbT = h2T + (size_t)b * DH * NPG;

    for (int c = tid; c < QTILE * 16; c += 256) {
        int row = c >> 4, seg = c & 15;
        int qrow = qt * QTILE + row;
        uint4 v = {0u, 0u, 0u, 0u};
        if (qrow < NPG) v = *(const uint4*)(hb + (size_t)qrow * DH + seg * 8);
        *(uint4*)&Qs[row][seg * 8] = v;
    }
    __syncthreads();

    bf16x8 aQ[4];
    int qr = wv * 16 + l15;
#pragma unroll
    for (int kb = 0; kb < 4; kb++)
        aQ[kb] = *(const bf16x8*)&Qs[qr][kb * 32 + quad * 8];

    float m_i[4], l_i[4];
    f32x4 O[8];
#pragma unroll
    for (int r = 0; r < 4; r++) { m_i[r] = -1e30f; l_i[r] = 0.0f; }
#pragma unroll
    for (int t = 0; t < 8; t++) O[t] = (f32x4){0.f, 0.f, 0.f, 0.f};

    for (int kt = 0; kt < 16; kt++) {
        __syncthreads();
        for (int c = tid; c < KTILE * 16; c += 256) {
            int row = c >> 4, seg = c & 15;
            int key = kt * KTILE + row;
            uint4 v = {0u, 0u, 0u, 0u};
            if (key < NPG) v = *(const uint4*)(hb + (size_t)key * DH + seg * 8);
            *(uint4*)&Ks[row][seg * 8] = v;
        }
        for (int c = tid; c < DH * 8; c += 256) {
            int dim = c >> 3, kc = c & 7;
            int key0 = kt * KTILE + kc * 8;
            uint4 v = {0u, 0u, 0u, 0u};
            if (key0 < NPG) v = *(const uint4*)(hbT + (size_t)dim * NPG + key0);
            *(uint4*)&Kt[dim][kc * 8] = v;
        }
        __syncthreads();

        f32x4 S[4];
#pragma unroll
        for (int nt = 0; nt < 4; nt++) {
            f32x4 acc = {0.f, 0.f, 0.f, 0.f};
#pragma unroll
            for (int kb = 0; kb < 4; kb++) {
                bf16x8 bK = *(const bf16x8*)&Ks[nt * 16 + l15][kb * 32 + quad * 8];
                acc = __builtin_amdgcn_mfma_f32_16x16x32_bf16(aQ[kb], bK, acc, 0, 0, 0);
            }
            S[nt] = acc;
        }

        float sm[4][4];
#pragma unroll
        for (int nt = 0; nt < 4; nt++) {
            int key = kt * KTILE + nt * 16 + l15;
            bool valid = key < NPG;
#pragma unroll
            for (int r = 0; r < 4; r++)
                sm[nt][r] = valid ? S[nt][r] * ATT_SCALE : -1e30f;
        }

        float tmax[4];
#pragma unroll
        for (int r = 0; r < 4; r++)
            tmax[r] = fmaxf(fmaxf(sm[0][r], sm[1][r]), fmaxf(sm[2][r], sm[3][r]));
#pragma unroll
        for (int off = 1; off < 16; off <<= 1)
#pragma unroll
            for (int r = 0; r < 4; r++) tmax[r] = fmaxf(tmax[r], __shfl_xor(tmax[r], off));

        float alpha[4], newm[4];
#pragma unroll
        for (int r = 0; r < 4; r++) {
            newm[r] = fmaxf(m_i[r], tmax[r]);
            alpha[r] = __expf(m_i[r] - newm[r]);
            m_i[r] = newm[r];
        }

        float ps[4][4];
        float rsum[4] = {0.f, 0.f, 0.f, 0.f};
#pragma unroll
        for (int nt = 0; nt < 4; nt++)
#pragma unroll
            for (int r = 0; r < 4; r++) {
                float p = __expf(sm[nt][r] - newm[r]);
                ps[nt][r] = p;
                rsum[r] += p;
            }
#pragma unroll
        for (int off = 1; off < 16; off <<= 1)
#pragma unroll
            for (int r = 0; r < 4; r++) rsum[r] += __shfl_xor(rsum[r], off);
#pragma unroll
        for (int r = 0; r < 4; r++) l_i[r] = l_i[r] * alpha[r] + rsum[r];

#pragma unroll
        for (int t = 0; t < 8; t++)
#pragma unroll
            for (int r = 0; r < 4; r++) O[t][r] *= alpha[r];

#pragma unroll
        for (int nt = 0; nt < 4; nt++)
#pragma unroll
            for (int r = 0; r < 4; r++)
                Ps[wv * 16 + quad * 4 + r][nt * 16 + l15] = (bf16_t)ps[nt][r];

#pragma unroll
        for (int kb2 = 0; kb2 < 2; kb2++) {
            bf16x8 aP = *(const bf16x8*)&Ps[wv * 16 + l15][kb2 * 32 + quad * 8];
#pragma unroll
            for (int t = 0; t < 8; t++) {
                bf16x8 bV = *(const bf16x8*)&Kt[t * 16 + l15][kb2 * 32 + quad * 8];
                O[t] = __builtin_amdgcn_mfma_f32_16x16x32_bf16(aP, bV, O[t], 0, 0, 0);
            }
        }
    }

    float invl[4];
#pragma unroll
    for (int r = 0; r < 4; r++) invl[r] = 1.0f / l_i[r];
    float* cb = ctx + (size_t)b * NPG * DH;
#pragma unroll
    for (int t = 0; t < 8; t++)
#pragma unroll
        for (int r = 0; r < 4; r++) {
            int qrow = qt * QTILE + wv * 16 + quad * 4 + r;
            if (qrow < NPG) cb[(size_t)qrow * DH + t * 16 + l15] = O[t][r] * invl[r];
        }
}

// ---------------------------------------------------------------------------
// Segmented max/mean pooling -> feat[B,12,512]
// ---------------------------------------------------------------------------
__global__ void pooling(const float* __restrict__ h1, const float* __restrict__ ctx,
                        float* __restrict__ feat) {
    int bs = blockIdx.x;
    int d = threadIdx.x;
    int base = bs * NSEG;
    float mx1 = -1e30f, sm1 = 0.f, mx2 = -1e30f, sm2 = 0.f;
    for (int n = 0; n < NSEG; n++) {
        float v1 = h1[(base + n) * DH + d];
        mx1 = fmaxf(mx1, v1);
        sm1 += v1;
        float v2 = ctx[(base + n) * DH + d];
        mx2 = fmaxf(mx2, v2);
        sm2 += v2;
    }
    const float invs = 1.0f / NSEG;
    feat[bs * 512 + d] = mx1;
    feat[bs * 512 + 128 + d] = sm1 * invs;
    feat[bs * 512 + 256 + d] = mx2;
    feat[bs * 512 + 384 + d] = sm2 * invs;
}

// ---------------------------------------------------------------------------
// MLP head
// ---------------------------------------------------------------------------
__global__ void mlp1(const float* __restrict__ feat, const float* __restrict__ wf1,
                     const float* __restrict__ bf1, float* __restrict__ y1raw) {
    int col = blockIdx.x * 256 + threadIdx.x;
    int r0 = blockIdx.y * 4;
    float bias = bf1[col];
    float a0 = bias, a1 = bias, a2 = bias, a3 = bias;
    const float* f0 = feat + (size_t)r0 * 6144;
    for (int k = 0; k < 6144; k++) {
        float w = wf1[k * 512 + col];
        a0 += f0[k] * w;
        a1 += f0[6144 + k] * w;
        a2 += f0[12288 + k] * w;
        a3 += f0[18432 + k] * w;
    }
    y1raw[(r0 + 0) * 512 + col] = a0;
    y1raw[(r0 + 1) * 512 + col] = a1;
    y1raw[(r0 + 2) * 512 + col] = a2;
    y1raw[(r0 + 3) * 512 + col] = a3;
}

__global__ void bn_silu(const float* __restrict__ raw, const float* __restrict__ g,
                        const float* __restrict__ be, float* __restrict__ out, int C) {
    int j = blockIdx.x;
    int b = threadIdx.x;
    float v = raw[b * C + j];
    float h = v / (1.0f + __expf(-v));
    float s = h, s2 = h * h;
    for (int off = 1; off < 64; off <<= 1) {
        s += __shfl_xor(s, off);
        s2 += __shfl_xor(s2, off);
    }
    float mu = s * (1.0f / 64.0f);
    float var = s2 * (1.0f / 64.0f) - mu * mu;
    float scale = rsqrtf(var + 1e-5f) * g[j];
    out[b * C + j] = (h - mu) * scale + be[j];
}

__global__ void mlp2(const float* __restrict__ y1, const float* __restrict__ wf2,
                     const float* __restrict__ bf2, float* __restrict__ y2raw) {
    int j = blockIdx.x;
    int b = threadIdx.x;
    float acc = bf2[j];
    for (int k = 0; k < 512; k++) acc += y1[b * 512 + k] * wf2[k * 32 + j];
    y2raw[b * 32 + j] = acc;
}

__global__ void mlp3(const float* __restrict__ y2, const float* __restrict__ wf3,
                     const float* __restrict__ bf3, float* __restrict__ out) {
    int b = threadIdx.x;
    float l0 = bf3[0], l1 = bf3[1];
    for (int k = 0; k < 32; k++) {
        float v = y2[b * 32 + k];
        l0 += v * wf3[k * 2 + 0];
        l1 += v * wf3[k * 2 + 1];
    }
    float m = fmaxf(l0, l1);
    float e0 = __expf(l0 - m), e1 = __expf(l1 - m);
    float inv = 1.0f / (e0 + e1);
    out[b * 2 + 0] = e0 * inv;
    out[b * 2 + 1] = e1 * inv;
}

// ---------------------------------------------------------------------------
extern "C" void kernel_launch(void* const* d_in, const int* in_sizes, int n_in,
                              void* d_out, int out_size, void* d_ws, size_t ws_size,
                              hipStream_t stream) {
    const float* x   = (const float*)d_in[0];
    const int*   ei  = (const int*)d_in[1];
    const float* w1  = (const float*)d_in[2];
    const float* b1  = (const float*)d_in[3];
    const float* w2  = (const float*)d_in[4];
    const float* b2  = (const float*)d_in[5];
    const float* pe  = (const float*)d_in[6];
    const float* wf1 = (const float*)d_in[7];
    const float* bf1 = (const float*)d_in[8];
    const float* g1  = (const float*)d_in[9];
    const float* be1 = (const float*)d_in[10];
    const float* wf2 = (const float*)d_in[11];
    const float* bf2 = (const float*)d_in[12];
    const float* g2  = (const float*)d_in[13];
    const float* be2 = (const float*)d_in[14];
    const float* wf3 = (const float*)d_in[15];
    const float* bf3 = (const float*)d_in[16];
    float* out = (float*)d_out;

    const int* srcp = ei;
    const int* dstp = ei + NEDGE;

    // workspace layout
    float* ws = (float*)d_ws;
    size_t off = 0;
    float* agg1 = ws + off; off += (size_t)N_NODES * DIN;
    float* agg2 = ws + off; off += (size_t)N_NODES * DH;
    float* h1   = ws + off; off += (size_t)N_NODES * DH;
    bf16_t* h2bf = (bf16_t*)(ws + off); off += (size_t)N_NODES * DH / 2;
    bf16_t* h2T  = (bf16_t*)(ws + off); off += (size_t)N_NODES * DH / 2;
    float* y1raw = ws + off; off += 64 * 512;
    float* y1    = ws + off; off += 64 * 512;
    float* y2raw = ws + off; off += 64 * 32;
    float* y2    = ws + off; off += 64 * 32;
    // int region for CSR
    int* deg  = (int*)(ws + off);            // N (also reused as cursor)
    int* offs = deg + N_NODES;               // N+1
    int* eidx = offs + N_NODES + 1;          // NEDGE
    float* ctxb = agg2;
    float* feat = agg1;

    // build CSR
    hipMemsetAsync(deg, 0, (size_t)N_NODES * sizeof(int), stream);
    count_deg<<<(NEDGE + 255) / 256, 256, 0, stream>>>(dstp, deg);
    scan_deg<<<1, 1024, 0, stream>>>(deg, offs);
    hipMemcpyAsync(deg, offs, (size_t)N_NODES * sizeof(int),
                   hipMemcpyDeviceToDevice, stream);  // deg becomes cursor
    fill_csr<<<(NEDGE + 255) / 256, 256, 0, stream>>>(srcp, dstp, deg, eidx);

    gather84<<<N_NODES / 4, 256, 0, stream>>>(x, offs, eidx, agg1);
    linear1<<<N_NODES / 8, 128, 0, stream>>>(x, agg1, w1, b1, h1);
    gather128<<<N_NODES / 2, 256, 0, stream>>>(h1, offs, eidx, agg2);
    linear2<<<N_NODES / 8, 128, 0, stream>>>(h1, agg2, w2, b2, pe, h2bf);
    transposeK<<<dim3(32, 4, BG), dim3(32, 8), 0, stream>>>(h2bf, h2T);
    attn_mfma<<<BG * 16, 256, 0, stream>>>(h2bf, h2T, ctxb);
    pooling<<<BG * NSNAP, 128, 0, stream>>>(h1, ctxb, feat);
    mlp1<<<dim3(2, 16), 256, 0, stream>>>(feat, wf1, bf1, y1raw);
    bn_silu<<<512, 64, 0, stream>>>(y1raw, g1, be1, y1, 512);
    mlp2<<<32, 64, 0, stream>>>(y1, wf2, bf2, y2raw);
    bn_silu<<<32, 64, 0, stream>>>(y2raw, g2, be2, y2, 32);
    mlp3<<<1, 64, 0, stream>>>(y2, wf3, bf3, out);
}

// Round 4
// 728.758 us; speedup vs baseline: 3.4220x; 1.4317x over previous
//
#include <hip/hip_runtime.h>
#include <math.h>

#define N_NODES 64512
#define DIN 84
#define DH 128
#define NPG 1008
#define BG 64
#define NSNAP 12
#define NSEG 84
#define NEDGE (N_NODES * 16)
#define ATT_SCALE 0.08838834764831845f /* 1/sqrt(128) */

typedef __bf16 bf16_t;
typedef __bf16 bf16x8 __attribute__((ext_vector_type(8)));
typedef float f32x4 __attribute__((ext_vector_type(4)));

// ---------------------------------------------------------------------------
// CSR build: degree count -> exclusive scan -> bucket fill
// ---------------------------------------------------------------------------
__global__ void count_deg(const int* __restrict__ dst, int* __restrict__ deg) {
    int e = blockIdx.x * blockDim.x + threadIdx.x;
    if (e < NEDGE) atomicAdd(&deg[dst[e]], 1);
}

__global__ __launch_bounds__(1024) void scan_deg(const int* __restrict__ deg,
                                                 int* __restrict__ off) {
    __shared__ int ssum[1024];
    int tid = threadIdx.x;
    int base = tid * 63;
    int s = 0;
#pragma unroll 7
    for (int j = 0; j < 63; j++) s += deg[base + j];
    ssum[tid] = s;
    __syncthreads();
    for (int d = 1; d < 1024; d <<= 1) {
        int v = (tid >= d) ? ssum[tid - d] : 0;
        __syncthreads();
        ssum[tid] += v;
        __syncthreads();
    }
    int run = (tid == 0) ? 0 : ssum[tid - 1];
#pragma unroll 7
    for (int j = 0; j < 63; j++) {
        off[base + j] = run;
        run += deg[base + j];
    }
    if (tid == 1023) off[N_NODES] = run;
}

__global__ void fill_csr(const int* __restrict__ src, const int* __restrict__ dst,
                         int* __restrict__ cursor, int* __restrict__ eidx) {
    int e = blockIdx.x * blockDim.x + threadIdx.x;
    if (e < NEDGE) {
        int p = atomicAdd(&cursor[dst[e]], 1);
        eidx[p] = src[e];
    }
}

// ---------------------------------------------------------------------------
// Gather aggregation: agg[i] = sum_j x[eidx[j]]
// ---------------------------------------------------------------------------
__global__ __launch_bounds__(256) void gather84(const float* __restrict__ x,
                                                const int* __restrict__ off,
                                                const int* __restrict__ eidx,
                                                float* __restrict__ agg) {
    int node = blockIdx.x * 4 + (threadIdx.x >> 6);
    int lane = threadIdx.x & 63;
    int s = off[node], e = off[node + 1];
    for (int f = lane; f < DIN; f += 64) {
        float acc = 0.f;
        int i = s;
        for (; i + 4 <= e; i += 4) {
            int i0 = eidx[i], i1 = eidx[i + 1], i2 = eidx[i + 2], i3 = eidx[i + 3];
            acc += x[(size_t)i0 * DIN + f] + x[(size_t)i1 * DIN + f] +
                   x[(size_t)i2 * DIN + f] + x[(size_t)i3 * DIN + f];
        }
        for (; i < e; i++) acc += x[(size_t)eidx[i] * DIN + f];
        agg[(size_t)node * DIN + f] = acc;
    }
}

__global__ __launch_bounds__(256) void gather128(const float* __restrict__ h,
                                                 const int* __restrict__ off,
                                                 const int* __restrict__ eidx,
                                                 float* __restrict__ agg) {
    int node = blockIdx.x * 2 + (threadIdx.x >> 7);
    int f = threadIdx.x & 127;
    int s = off[node], e = off[node + 1];
    float acc = 0.f;
    int i = s;
    for (; i + 4 <= e; i += 4) {
        int i0 = eidx[i], i1 = eidx[i + 1], i2 = eidx[i + 2], i3 = eidx[i + 3];
        acc += h[(size_t)i0 * DH + f] + h[(size_t)i1 * DH + f] +
               h[(size_t)i2 * DH + f] + h[(size_t)i3 * DH + f];
    }
    for (; i < e; i++) acc += h[(size_t)eidx[i] * DH + f];
    agg[(size_t)node * DH + f] = acc;
}

// ---------------------------------------------------------------------------
// h1 = (x + agg1) @ w1 + b1
// ---------------------------------------------------------------------------
__global__ void linear1(const float* __restrict__ x, const float* __restrict__ agg,
                        const float* __restrict__ w1, const float* __restrict__ b1,
                        float* __restrict__ h1) {
    __shared__ float xs[8][DIN];
    int n0 = blockIdx.x * 8;
    int tid = threadIdx.x;
    for (int i = tid; i < 8 * DIN; i += 128) {
        int r = i / DIN, f = i - r * DIN;
        int node = n0 + r;
        xs[r][f] = x[node * DIN + f] + agg[node * DIN + f];
    }
    __syncthreads();
    float acc[8];
    float bias = b1[tid];
#pragma unroll
    for (int r = 0; r < 8; r++) acc[r] = bias;
    for (int k = 0; k < DIN; k++) {
        float w = w1[k * DH + tid];
#pragma unroll
        for (int r = 0; r < 8; r++) acc[r] += xs[r][k] * w;
    }
#pragma unroll
    for (int r = 0; r < 8; r++) h1[(n0 + r) * DH + tid] = acc[r];
}

// ---------------------------------------------------------------------------
// h2bf = bf16( (h1 + agg2) @ w2 + b2 + pe[node % 1008] )
// ---------------------------------------------------------------------------
__global__ void linear2(const float* __restrict__ h1, const float* __restrict__ agg,
                        const float* __restrict__ w2, const float* __restrict__ b2,
                        const float* __restrict__ pe, bf16_t* __restrict__ h2bf) {
    __shared__ float hs[8][DH];
    int n0 = blockIdx.x * 8;
    int tid = threadIdx.x;
    for (int i = tid; i < 8 * DH; i += 128) {
        int r = i >> 7, f = i & 127;
        int node = n0 + r;
        hs[r][f] = h1[node * DH + f] + agg[node * DH + f];
    }
    __syncthreads();
    float acc[8];
    float bias = b2[tid];
#pragma unroll
    for (int r = 0; r < 8; r++) acc[r] = bias;
    for (int k = 0; k < DH; k++) {
        float w = w2[k * DH + tid];
#pragma unroll
        for (int r = 0; r < 8; r++) acc[r] += hs[r][k] * w;
    }
#pragma unroll
    for (int r = 0; r < 8; r++) {
        int node = n0 + r;
        int pos = node % NPG;
        h2bf[(size_t)node * DH + tid] = (bf16_t)(acc[r] + pe[pos * DH + tid]);
    }
}

// ---------------------------------------------------------------------------
// h2T[b][d][k] = h2bf[b*1008 + k][d]
// ---------------------------------------------------------------------------
__global__ void transposeK(const bf16_t* __restrict__ h2bf, bf16_t* __restrict__ h2T) {
    __shared__ bf16_t tile[32][34];
    int b = blockIdx.z;
    int k0 = blockIdx.x * 32;
    int d0 = blockIdx.y * 32;
    int tx = threadIdx.x;
    int ty = threadIdx.y;
    for (int i = ty; i < 32; i += 8) {
        int k = k0 + i;
        tile[i][tx] = (k < NPG) ? h2bf[((size_t)b * NPG + k) * DH + d0 + tx] : (bf16_t)0.0f;
    }
    __syncthreads();
    for (int i = ty; i < 32; i += 8) {
        int k = k0 + tx;
        if (k < NPG) h2T[((size_t)b * DH + d0 + i) * NPG + k] = tile[tx][i];
    }
}

// ---------------------------------------------------------------------------
// Flash-style MFMA attention (unchanged)
// ---------------------------------------------------------------------------
#define QTILE 64
#define KTILE 64
#define QK_PITCH 136
#define KT_PITCH 72

__global__ __launch_bounds__(256) void attn_mfma(const bf16_t* __restrict__ h2bf,
                                                 const bf16_t* __restrict__ h2T,
                                                 float* __restrict__ ctx) {
    __shared__ bf16_t Qs[QTILE][QK_PITCH];
    __shared__ bf16_t Ks[KTILE][QK_PITCH];
    __shared__ bf16_t Kt[DH][KT_PITCH];
    __shared__ bf16_t Ps[QTILE][KT_PITCH];

    int tid = threadIdx.x;
    int wv = tid >> 6, lane = tid & 63;
    int l15 = lane & 15, quad = lane >> 4;
    int b = blockIdx.x >> 4;
    int qt = blockIdx.x & 15;
    const bf16_t* hb = h2bf + (size_t)b * NPG * DH;
    const bf16_t* hbT = h2T + (size_t)b * DH * NPG;

    for (int c = tid; c < QTILE * 16; c += 256) {
        int row = c >> 4, seg = c & 15;
        int qrow = qt * QTILE + row;
        uint4 v = {0u, 0u, 0u, 0u};
        if (qrow < NPG) v = *(const uint4*)(hb + (size_t)qrow * DH + seg * 8);
        *(uint4*)&Qs[row][seg * 8] = v;
    }
    __syncthreads();

    bf16x8 aQ[4];
    int qr = wv * 16 + l15;
#pragma unroll
    for (int kb = 0; kb < 4; kb++)
        aQ[kb] = *(const bf16x8*)&Qs[qr][kb * 32 + quad * 8];

    float m_i[4], l_i[4];
    f32x4 O[8];
#pragma unroll
    for (int r = 0; r < 4; r++) { m_i[r] = -1e30f; l_i[r] = 0.0f; }
#pragma unroll
    for (int t = 0; t < 8; t++) O[t] = (f32x4){0.f, 0.f, 0.f, 0.f};

    for (int kt = 0; kt < 16; kt++) {
        __syncthreads();
        for (int c = tid; c < KTILE * 16; c += 256) {
            int row = c >> 4, seg = c & 15;
            int key = kt * KTILE + row;
            uint4 v = {0u, 0u, 0u, 0u};
            if (key < NPG) v = *(const uint4*)(hb + (size_t)key * DH + seg * 8);
            *(uint4*)&Ks[row][seg * 8] = v;
        }
        for (int c = tid; c < DH * 8; c += 256) {
            int dim = c >> 3, kc = c & 7;
            int key0 = kt * KTILE + kc * 8;
            uint4 v = {0u, 0u, 0u, 0u};
            if (key0 < NPG) v = *(const uint4*)(hbT + (size_t)dim * NPG + key0);
            *(uint4*)&Kt[dim][kc * 8] = v;
        }
        __syncthreads();

        f32x4 S[4];
#pragma unroll
        for (int nt = 0; nt < 4; nt++) {
            f32x4 acc = {0.f, 0.f, 0.f, 0.f};
#pragma unroll
            for (int kb = 0; kb < 4; kb++) {
                bf16x8 bK = *(const bf16x8*)&Ks[nt * 16 + l15][kb * 32 + quad * 8];
                acc = __builtin_amdgcn_mfma_f32_16x16x32_bf16(aQ[kb], bK, acc, 0, 0, 0);
            }
            S[nt] = acc;
        }

        float sm[4][4];
#pragma unroll
        for (int nt = 0; nt < 4; nt++) {
            int key = kt * KTILE + nt * 16 + l15;
            bool valid = key < NPG;
#pragma unroll
            for (int r = 0; r < 4; r++)
                sm[nt][r] = valid ? S[nt][r] * ATT_SCALE : -1e30f;
        }

        float tmax[4];
#pragma unroll
        for (int r = 0; r < 4; r++)
            tmax[r] = fmaxf(fmaxf(sm[0][r], sm[1][r]), fmaxf(sm[2][r], sm[3][r]));
#pragma unroll
        for (int off = 1; off < 16; off <<= 1)
#pragma unroll
            for (int r = 0; r < 4; r++) tmax[r] = fmaxf(tmax[r], __shfl_xor(tmax[r], off));

        float alpha[4], newm[4];
#pragma unroll
        for (int r = 0; r < 4; r++) {
            newm[r] = fmaxf(m_i[r], tmax[r]);
            alpha[r] = __expf(m_i[r] - newm[r]);
            m_i[r] = newm[r];
        }

        float ps[4][4];
        float rsum[4] = {0.f, 0.f, 0.f, 0.f};
#pragma unroll
        for (int nt = 0; nt < 4; nt++)
#pragma unroll
            for (int r = 0; r < 4; r++) {
                float p = __expf(sm[nt][r] - newm[r]);
                ps[nt][r] = p;
                rsum[r] += p;
            }
#pragma unroll
        for (int off = 1; off < 16; off <<= 1)
#pragma unroll
            for (int r = 0; r < 4; r++) rsum[r] += __shfl_xor(rsum[r], off);
#pragma unroll
        for (int r = 0; r < 4; r++) l_i[r] = l_i[r] * alpha[r] + rsum[r];

#pragma unroll
        for (int t = 0; t < 8; t++)
#pragma unroll
            for (int r = 0; r < 4; r++) O[t][r] *= alpha[r];

#pragma unroll
        for (int nt = 0; nt < 4; nt++)
#pragma unroll
            for (int r = 0; r < 4; r++)
                Ps[wv * 16 + quad * 4 + r][nt * 16 + l15] = (bf16_t)ps[nt][r];

#pragma unroll
        for (int kb2 = 0; kb2 < 2; kb2++) {
            bf16x8 aP = *(const bf16x8*)&Ps[wv * 16 + l15][kb2 * 32 + quad * 8];
#pragma unroll
            for (int t = 0; t < 8; t++) {
                bf16x8 bV = *(const bf16x8*)&Kt[t * 16 + l15][kb2 * 32 + quad * 8];
                O[t] = __builtin_amdgcn_mfma_f32_16x16x32_bf16(aP, bV, O[t], 0, 0, 0);
            }
        }
    }

    float invl[4];
#pragma unroll
    for (int r = 0; r < 4; r++) invl[r] = 1.0f / l_i[r];
    float* cb = ctx + (size_t)b * NPG * DH;
#pragma unroll
    for (int t = 0; t < 8; t++)
#pragma unroll
        for (int r = 0; r < 4; r++) {
            int qrow = qt * QTILE + wv * 16 + quad * 4 + r;
            if (qrow < NPG) cb[(size_t)qrow * DH + t * 16 + l15] = O[t][r] * invl[r];
        }
}

// ---------------------------------------------------------------------------
// Segmented max/mean pooling -> feat[B,12,512]
// ---------------------------------------------------------------------------
__global__ void pooling(const float* __restrict__ h1, const float* __restrict__ ctx,
                        float* __restrict__ feat) {
    int bs = blockIdx.x;
    int d = threadIdx.x;
    int base = bs * NSEG;
    float mx1 = -1e30f, sm1 = 0.f, mx2 = -1e30f, sm2 = 0.f;
    for (int n = 0; n < NSEG; n++) {
        float v1 = h1[(base + n) * DH + d];
        mx1 = fmaxf(mx1, v1);
        sm1 += v1;
        float v2 = ctx[(base + n) * DH + d];
        mx2 = fmaxf(mx2, v2);
        sm2 += v2;
    }
    const float invs = 1.0f / NSEG;
    feat[bs * 512 + d] = mx1;
    feat[bs * 512 + 128 + d] = sm1 * invs;
    feat[bs * 512 + 256 + d] = mx2;
    feat[bs * 512 + 384 + d] = sm2 * invs;
}

// ---------------------------------------------------------------------------
// MLP head: y1raw = bias; then split-K GEMM with fp32 atomic accumulation
// ---------------------------------------------------------------------------
__global__ void init_y1(const float* __restrict__ bf1, float* __restrict__ y1raw) {
    int i = blockIdx.x * 256 + threadIdx.x;  // 32768 = 64*512
    y1raw[i] = bf1[i & 511];
}

#define MLP1_KCH 96
__global__ __launch_bounds__(256) void mlp1_splitk(const float* __restrict__ feat,
                                                   const float* __restrict__ wf1,
                                                   float* __restrict__ y1raw) {
    __shared__ float fl[64][MLP1_KCH];  // 24 KB
    int k0 = blockIdx.y * MLP1_KCH;
    int tid = threadIdx.x;
    for (int c = tid; c < 64 * MLP1_KCH; c += 256) {
        int row = c / MLP1_KCH;
        int kk = c - row * MLP1_KCH;
        fl[row][kk] = feat[(size_t)row * 6144 + k0 + kk];
    }
    __syncthreads();
    int col = blockIdx.x * 128 + (tid & 127);
    int rbase = (tid >> 7) * 32;  // 0 or 32
    float acc[32];
#pragma unroll
    for (int r = 0; r < 32; r++) acc[r] = 0.f;
    for (int kg = 0; kg < MLP1_KCH; kg += 4) {
        float w0 = wf1[(size_t)(k0 + kg + 0) * 512 + col];
        float w1 = wf1[(size_t)(k0 + kg + 1) * 512 + col];
        float w2 = wf1[(size_t)(k0 + kg + 2) * 512 + col];
        float w3 = wf1[(size_t)(k0 + kg + 3) * 512 + col];
#pragma unroll
        for (int r = 0; r < 32; r++) {
            float4 f = *(const float4*)&fl[rbase + r][kg];
            acc[r] += f.x * w0 + f.y * w1 + f.z * w2 + f.w * w3;
        }
    }
#pragma unroll
    for (int r = 0; r < 32; r++)
        atomicAdd(&y1raw[(size_t)(rbase + r) * 512 + col], acc[r]);
}

__global__ void bn_silu(const float* __restrict__ raw, const float* __restrict__ g,
                        const float* __restrict__ be, float* __restrict__ out, int C) {
    int j = blockIdx.x;
    int b = threadIdx.x;
    float v = raw[b * C + j];
    float h = v / (1.0f + __expf(-v));
    float s = h, s2 = h * h;
    for (int off = 1; off < 64; off <<= 1) {
        s += __shfl_xor(s, off);
        s2 += __shfl_xor(s2, off);
    }
    float mu = s * (1.0f / 64.0f);
    float var = s2 * (1.0f / 64.0f) - mu * mu;
    float scale = rsqrtf(var + 1e-5f) * g[j];
    out[b * C + j] = (h - mu) * scale + be[j];
}

__global__ void mlp2(const float* __restrict__ y1, const float* __restrict__ wf2,
                     const float* __restrict__ bf2, float* __restrict__ y2raw) {
    int j = blockIdx.x;
    int b = threadIdx.x;
    float acc = bf2[j];
    for (int k = 0; k < 512; k++) acc += y1[b * 512 + k] * wf2[k * 32 + j];
    y2raw[b * 32 + j] = acc;
}

__global__ void mlp3(const float* __restrict__ y2, const float* __restrict__ wf3,
                     const float* __restrict__ bf3, float* __restrict__ out) {
    int b = threadIdx.x;
    float l0 = bf3[0], l1 = bf3[1];
    for (int k = 0; k < 32; k++) {
        float v = y2[b * 32 + k];
        l0 += v * wf3[k * 2 + 0];
        l1 += v * wf3[k * 2 + 1];
    }
    float m = fmaxf(l0, l1);
    float e0 = __expf(l0 - m), e1 = __expf(l1 - m);
    float inv = 1.0f / (e0 + e1);
    out[b * 2 + 0] = e0 * inv;
    out[b * 2 + 1] = e1 * inv;
}

// ---------------------------------------------------------------------------
extern "C" void kernel_launch(void* const* d_in, const int* in_sizes, int n_in,
                              void* d_out, int out_size, void* d_ws, size_t ws_size,
                              hipStream_t stream) {
    const float* x   = (const float*)d_in[0];
    const int*   ei  = (const int*)d_in[1];
    const float* w1  = (const float*)d_in[2];
    const float* b1  = (const float*)d_in[3];
    const float* w2  = (const float*)d_in[4];
    const float* b2  = (const float*)d_in[5];
    const float* pe  = (const float*)d_in[6];
    const float* wf1 = (const float*)d_in[7];
    const float* bf1 = (const float*)d_in[8];
    const float* g1  = (const float*)d_in[9];
    const float* be1 = (const float*)d_in[10];
    const float* wf2 = (const float*)d_in[11];
    const float* bf2 = (const float*)d_in[12];
    const float* g2  = (const float*)d_in[13];
    const float* be2 = (const float*)d_in[14];
    const float* wf3 = (const float*)d_in[15];
    const float* bf3 = (const float*)d_in[16];
    float* out = (float*)d_out;

    const int* srcp = ei;
    const int* dstp = ei + NEDGE;

    // workspace layout
    float* ws = (float*)d_ws;
    size_t off = 0;
    float* agg1 = ws + off; off += (size_t)N_NODES * DIN;
    float* agg2 = ws + off; off += (size_t)N_NODES * DH;
    float* h1   = ws + off; off += (size_t)N_NODES * DH;
    bf16_t* h2bf = (bf16_t*)(ws + off); off += (size_t)N_NODES * DH / 2;
    bf16_t* h2T  = (bf16_t*)(ws + off); off += (size_t)N_NODES * DH / 2;
    float* y1raw = ws + off; off += 64 * 512;
    float* y1    = ws + off; off += 64 * 512;
    float* y2raw = ws + off; off += 64 * 32;
    float* y2    = ws + off; off += 64 * 32;
    int* deg  = (int*)(ws + off);
    int* offs = deg + N_NODES;
    int* eidx = offs + N_NODES + 1;
    float* ctxb = agg2;
    float* feat = agg1;

    // build CSR
    hipMemsetAsync(deg, 0, (size_t)N_NODES * sizeof(int), stream);
    count_deg<<<(NEDGE + 255) / 256, 256, 0, stream>>>(dstp, deg);
    scan_deg<<<1, 1024, 0, stream>>>(deg, offs);
    hipMemcpyAsync(deg, offs, (size_t)N_NODES * sizeof(int),
                   hipMemcpyDeviceToDevice, stream);
    fill_csr<<<(NEDGE + 255) / 256, 256, 0, stream>>>(srcp, dstp, deg, eidx);

    gather84<<<N_NODES / 4, 256, 0, stream>>>(x, offs, eidx, agg1);
    linear1<<<N_NODES / 8, 128, 0, stream>>>(x, agg1, w1, b1, h1);
    gather128<<<N_NODES / 2, 256, 0, stream>>>(h1, offs, eidx, agg2);
    linear2<<<N_NODES / 8, 128, 0, stream>>>(h1, agg2, w2, b2, pe, h2bf);
    transposeK<<<dim3(32, 4, BG), dim3(32, 8), 0, stream>>>(h2bf, h2T);
    attn_mfma<<<BG * 16, 256, 0, stream>>>(h2bf, h2T, ctxb);
    pooling<<<BG * NSNAP, 128, 0, stream>>>(h1, ctxb, feat);
    init_y1<<<128, 256, 0, stream>>>(bf1, y1raw);
    mlp1_splitk<<<dim3(4, 64), 256, 0, stream>>>(feat, wf1, y1raw);
    bn_silu<<<512, 64, 0, stream>>>(y1raw, g1, be1, y1, 512);
    mlp2<<<32, 64, 0, stream>>>(y1, wf2, bf2, y2raw);
    bn_silu<<<32, 64, 0, stream>>>(y2raw, g2, be2, y2, 32);
    mlp3<<<1, 64, 0, stream>>>(y2, wf3, bf3, out);
}

// Round 5
// 708.704 us; speedup vs baseline: 3.5188x; 1.0283x over previous
//
#include <hip/hip_runtime.h>
#include <math.h>

#define N_NODES 64512
#define DIN 84
#define DH 128
#define NPG 1008
#define BG 64
#define NSNAP 12
#define NSEG 84
#define NEDGE (N_NODES * 16)
#define ATT_SCALE 0.08838834764831845f /* 1/sqrt(128) */

typedef __bf16 bf16_t;
typedef __bf16 bf16x8 __attribute__((ext_vector_type(8)));
typedef __bf16 bf16x4 __attribute__((ext_vector_type(4)));
typedef float f32x4 __attribute__((ext_vector_type(4)));

// ---------------------------------------------------------------------------
// CSR build: degree count -> exclusive scan -> bucket fill
// ---------------------------------------------------------------------------
__global__ void count_deg(const int* __restrict__ dst, int* __restrict__ deg) {
    int e = blockIdx.x * blockDim.x + threadIdx.x;
    if (e < NEDGE) atomicAdd(&deg[dst[e]], 1);
}

__global__ __launch_bounds__(1024) void scan_deg(const int* __restrict__ deg,
                                                 int* __restrict__ off) {
    __shared__ int ssum[1024];
    int tid = threadIdx.x;
    int base = tid * 63;
    int s = 0;
#pragma unroll 7
    for (int j = 0; j < 63; j++) s += deg[base + j];
    ssum[tid] = s;
    __syncthreads();
    for (int d = 1; d < 1024; d <<= 1) {
        int v = (tid >= d) ? ssum[tid - d] : 0;
        __syncthreads();
        ssum[tid] += v;
        __syncthreads();
    }
    int run = (tid == 0) ? 0 : ssum[tid - 1];
#pragma unroll 7
    for (int j = 0; j < 63; j++) {
        off[base + j] = run;
        run += deg[base + j];
    }
    if (tid == 1023) off[N_NODES] = run;
}

__global__ void fill_csr(const int* __restrict__ src, const int* __restrict__ dst,
                         int* __restrict__ cursor, int* __restrict__ eidx) {
    int e = blockIdx.x * blockDim.x + threadIdx.x;
    if (e < NEDGE) {
        int p = atomicAdd(&cursor[dst[e]], 1);
        eidx[p] = src[e];
    }
}

// ---------------------------------------------------------------------------
// Gather aggregation: agg[i] = sum_j x[eidx[j]]
// ---------------------------------------------------------------------------
__global__ __launch_bounds__(256) void gather84(const float* __restrict__ x,
                                                const int* __restrict__ off,
                                                const int* __restrict__ eidx,
                                                float* __restrict__ agg) {
    int node = blockIdx.x * 4 + (threadIdx.x >> 6);
    int lane = threadIdx.x & 63;
    int s = off[node], e = off[node + 1];
    for (int f = lane; f < DIN; f += 64) {
        float acc = 0.f;
        int i = s;
        for (; i + 4 <= e; i += 4) {
            int i0 = eidx[i], i1 = eidx[i + 1], i2 = eidx[i + 2], i3 = eidx[i + 3];
            acc += x[(size_t)i0 * DIN + f] + x[(size_t)i1 * DIN + f] +
                   x[(size_t)i2 * DIN + f] + x[(size_t)i3 * DIN + f];
        }
        for (; i < e; i++) acc += x[(size_t)eidx[i] * DIN + f];
        agg[(size_t)node * DIN + f] = acc;
    }
}

__global__ __launch_bounds__(256) void gather128(const float* __restrict__ h,
                                                 const int* __restrict__ off,
                                                 const int* __restrict__ eidx,
                                                 float* __restrict__ agg) {
    int node = blockIdx.x * 2 + (threadIdx.x >> 7);
    int f = threadIdx.x & 127;
    int s = off[node], e = off[node + 1];
    float acc = 0.f;
    int i = s;
    for (; i + 4 <= e; i += 4) {
        int i0 = eidx[i], i1 = eidx[i + 1], i2 = eidx[i + 2], i3 = eidx[i + 3];
        acc += h[(size_t)i0 * DH + f] + h[(size_t)i1 * DH + f] +
               h[(size_t)i2 * DH + f] + h[(size_t)i3 * DH + f];
    }
    for (; i < e; i++) acc += h[(size_t)eidx[i] * DH + f];
    agg[(size_t)node * DH + f] = acc;
}

// ---------------------------------------------------------------------------
// h1 = (x + agg1) @ w1 + b1
// ---------------------------------------------------------------------------
__global__ void linear1(const float* __restrict__ x, const float* __restrict__ agg,
                        const float* __restrict__ w1, const float* __restrict__ b1,
                        float* __restrict__ h1) {
    __shared__ float xs[8][DIN];
    int n0 = blockIdx.x * 8;
    int tid = threadIdx.x;
    for (int i = tid; i < 8 * DIN; i += 128) {
        int r = i / DIN, f = i - r * DIN;
        int node = n0 + r;
        xs[r][f] = x[node * DIN + f] + agg[node * DIN + f];
    }
    __syncthreads();
    float acc[8];
    float bias = b1[tid];
#pragma unroll
    for (int r = 0; r < 8; r++) acc[r] = bias;
    for (int k = 0; k < DIN; k++) {
        float w = w1[k * DH + tid];
#pragma unroll
        for (int r = 0; r < 8; r++) acc[r] += xs[r][k] * w;
    }
#pragma unroll
    for (int r = 0; r < 8; r++) h1[(n0 + r) * DH + tid] = acc[r];
}

// ---------------------------------------------------------------------------
// h2bf = bf16( (h1 + agg2) @ w2 + b2 + pe[node % 1008] )
// ---------------------------------------------------------------------------
__global__ void linear2(const float* __restrict__ h1, const float* __restrict__ agg,
                        const float* __restrict__ w2, const float* __restrict__ b2,
                        const float* __restrict__ pe, bf16_t* __restrict__ h2bf) {
    __shared__ float hs[8][DH];
    int n0 = blockIdx.x * 8;
    int tid = threadIdx.x;
    for (int i = tid; i < 8 * DH; i += 128) {
        int r = i >> 7, f = i & 127;
        int node = n0 + r;
        hs[r][f] = h1[node * DH + f] + agg[node * DH + f];
    }
    __syncthreads();
    float acc[8];
    float bias = b2[tid];
#pragma unroll
    for (int r = 0; r < 8; r++) acc[r] = bias;
    for (int k = 0; k < DH; k++) {
        float w = w2[k * DH + tid];
#pragma unroll
        for (int r = 0; r < 8; r++) acc[r] += hs[r][k] * w;
    }
#pragma unroll
    for (int r = 0; r < 8; r++) {
        int node = n0 + r;
        int pos = node % NPG;
        h2bf[(size_t)node * DH + tid] = (bf16_t)(acc[r] + pe[pos * DH + tid]);
    }
}

// ---------------------------------------------------------------------------
// h2T[b][d][k] = h2bf[b*1008 + k][d]
// ---------------------------------------------------------------------------
__global__ void transposeK(const bf16_t* __restrict__ h2bf, bf16_t* __restrict__ h2T) {
    __shared__ bf16_t tile[32][34];
    int b = blockIdx.z;
    int k0 = blockIdx.x * 32;
    int d0 = blockIdx.y * 32;
    int tx = threadIdx.x;
    int ty = threadIdx.y;
    for (int i = ty; i < 32; i += 8) {
        int k = k0 + i;
        tile[i][tx] = (k < NPG) ? h2bf[((size_t)b * NPG + k) * DH + d0 + tx] : (bf16_t)0.0f;
    }
    __syncthreads();
    for (int i = ty; i < 32; i += 8) {
        int k = k0 + tx;
        if (k < NPG) h2T[((size_t)b * DH + d0 + i) * NPG + k] = tile[tx][i];
    }
}

// ---------------------------------------------------------------------------
// Flash-style MFMA attention, S^T formulation.
//   QK^T: A = K rows (Ks), B = Q fragments (from global, held in regs)
//         -> S^T C-layout: col(l15) = q, row(quad*4+r) = key
//         -> softmax reduces over keys: in-lane + shfl(16,32); scalar m/l/alpha
//   P written as Ps[q][key] (packed bf16x4), PV: A = Ps, B = Kt (unchanged)
// LDS = Ks + Kt + Ps = 45 KB -> 3 blocks/CU.
// ---------------------------------------------------------------------------
#define QTILE 64
#define KTILE 64
#define KS_PITCH 136
#define KT_PITCH 72
#define PS_PITCH 72

__global__ __launch_bounds__(256, 3) void attn_mfma(const bf16_t* __restrict__ h2bf,
                                                    const bf16_t* __restrict__ h2T,
                                                    float* __restrict__ ctx) {
    __shared__ bf16_t Ks[KTILE][KS_PITCH];   // 17408 B
    __shared__ bf16_t Kt[DH][KT_PITCH];      // 18432 B
    __shared__ bf16_t Ps[QTILE][PS_PITCH];   //  9216 B

    int tid = threadIdx.x;
    int wv = tid >> 6, lane = tid & 63;
    int l15 = lane & 15, quad = lane >> 4;
    int b = blockIdx.x >> 4;
    int qt = blockIdx.x & 15;
    const bf16_t* hb = h2bf + (size_t)b * NPG * DH;
    const bf16_t* hbT = h2T + (size_t)b * DH * NPG;

    // ---- Q B-fragments direct from global: lane l15 = q row, quad*8 = dim ----
    int qrow_frag = qt * QTILE + wv * 16 + l15;
    int qsrc = (qrow_frag < NPG) ? qrow_frag : 0;  // clamped; invalid cols never stored
    bf16x8 bQ[4];
#pragma unroll
    for (int kb = 0; kb < 4; kb++)
        bQ[kb] = *(const bf16x8*)(hb + (size_t)qsrc * DH + kb * 32 + quad * 8);

    float m_i = -1e30f, l_i = 0.0f;  // state for q = wv*16 + l15
    f32x4 O[8];
#pragma unroll
    for (int t = 0; t < 8; t++) O[t] = (f32x4){0.f, 0.f, 0.f, 0.f};

    for (int kt = 0; kt < 16; kt++) {
        __syncthreads();
        // ---- stage K tile: Ks[key][dim] and Kt[dim][key] ----
        for (int c = tid; c < KTILE * 16; c += 256) {
            int row = c >> 4, seg = c & 15;
            int key = kt * KTILE + row;
            uint4 v = {0u, 0u, 0u, 0u};
            if (key < NPG) v = *(const uint4*)(hb + (size_t)key * DH + seg * 8);
            *(uint4*)&Ks[row][seg * 8] = v;
        }
        for (int c = tid; c < DH * 8; c += 256) {
            int dim = c >> 3, kc = c & 7;
            int key0 = kt * KTILE + kc * 8;
            uint4 v = {0u, 0u, 0u, 0u};
            if (key0 < NPG) v = *(const uint4*)(hbT + (size_t)dim * NPG + key0);
            *(uint4*)&Kt[dim][kc * 8] = v;
        }
        __syncthreads();

        // ---- S^T = K Q^T : D[m=key][n=q] ----
        f32x4 S[4];
#pragma unroll
        for (int nt = 0; nt < 4; nt++) {
            f32x4 acc = {0.f, 0.f, 0.f, 0.f};
#pragma unroll
            for (int kb = 0; kb < 4; kb++) {
                bf16x8 aK = *(const bf16x8*)&Ks[nt * 16 + l15][kb * 32 + quad * 8];
                acc = __builtin_amdgcn_mfma_f32_16x16x32_bf16(aK, bQ[kb], acc, 0, 0, 0);
            }
            S[nt] = acc;
        }

        // ---- scale + tile-uniform mask + in-lane partial max over keys ----
        float sm[4][4];
        float pmax = -1e30f;
#pragma unroll
        for (int nt = 0; nt < 4; nt++) {
            bool valid = (kt * KTILE + nt * 16) < NPG;  // 1008 = 63*16: whole tiles
#pragma unroll
            for (int r = 0; r < 4; r++) {
                float v = valid ? S[nt][r] * ATT_SCALE : -1e30f;
                sm[nt][r] = v;
                pmax = fmaxf(pmax, v);
            }
        }
        pmax = fmaxf(pmax, __shfl_xor(pmax, 16));
        pmax = fmaxf(pmax, __shfl_xor(pmax, 32));
        float newm = fmaxf(m_i, pmax);
        float alpha = __expf(m_i - newm);
        m_i = newm;

        // ---- P = exp(S^T - m), in-lane + cross-quad sum ----
        float pp[4][4];
        float psum = 0.f;
#pragma unroll
        for (int nt = 0; nt < 4; nt++)
#pragma unroll
            for (int r = 0; r < 4; r++) {
                float p = __expf(sm[nt][r] - newm);
                pp[nt][r] = p;
                psum += p;
            }
        psum += __shfl_xor(psum, 16);
        psum += __shfl_xor(psum, 32);
        l_i = l_i * alpha + psum;

        // ---- write P into Ps[q][key], packed 8B stores (wave-private rows) ----
#pragma unroll
        for (int nt = 0; nt < 4; nt++) {
            bf16x4 pk;
#pragma unroll
            for (int r = 0; r < 4; r++) pk[r] = (bf16_t)pp[nt][r];
            *(bf16x4*)&Ps[wv * 16 + l15][nt * 16 + quad * 4] = pk;
        }

        // ---- rescale O: alpha for q = quad*4+r via broadcast ----
        float a0 = __shfl(alpha, quad * 4 + 0);
        float a1 = __shfl(alpha, quad * 4 + 1);
        float a2 = __shfl(alpha, quad * 4 + 2);
        float a3 = __shfl(alpha, quad * 4 + 3);
#pragma unroll
        for (int t = 0; t < 8; t++) {
            O[t][0] *= a0; O[t][1] *= a1; O[t][2] *= a2; O[t][3] *= a3;
        }

        // ---- O += P V ----
#pragma unroll
        for (int kb2 = 0; kb2 < 2; kb2++) {
            bf16x8 aP = *(const bf16x8*)&Ps[wv * 16 + l15][kb2 * 32 + quad * 8];
#pragma unroll
            for (int t = 0; t < 8; t++) {
                bf16x8 bV = *(const bf16x8*)&Kt[t * 16 + l15][kb2 * 32 + quad * 8];
                O[t] = __builtin_amdgcn_mfma_f32_16x16x32_bf16(aP, bV, O[t], 0, 0, 0);
            }
        }
    }

    // ---- epilogue ----
    float invl[4];
#pragma unroll
    for (int r = 0; r < 4; r++) invl[r] = 1.0f / __shfl(l_i, quad * 4 + r);
    float* cb = ctx + (size_t)b * NPG * DH;
#pragma unroll
    for (int t = 0; t < 8; t++)
#pragma unroll
        for (int r = 0; r < 4; r++) {
            int qrow = qt * QTILE + wv * 16 + quad * 4 + r;
            if (qrow < NPG) cb[(size_t)qrow * DH + t * 16 + l15] = O[t][r] * invl[r];
        }
}

// ---------------------------------------------------------------------------
// Segmented max/mean pooling -> feat[B,12,512]
// ---------------------------------------------------------------------------
__global__ void pooling(const float* __restrict__ h1, const float* __restrict__ ctx,
                        float* __restrict__ feat) {
    int bs = blockIdx.x;
    int d = threadIdx.x;
    int base = bs * NSEG;
    float mx1 = -1e30f, sm1 = 0.f, mx2 = -1e30f, sm2 = 0.f;
    for (int n = 0; n < NSEG; n++) {
        float v1 = h1[(base + n) * DH + d];
        mx1 = fmaxf(mx1, v1);
        sm1 += v1;
        float v2 = ctx[(base + n) * DH + d];
        mx2 = fmaxf(mx2, v2);
        sm2 += v2;
    }
    const float invs = 1.0f / NSEG;
    feat[bs * 512 + d] = mx1;
    feat[bs * 512 + 128 + d] = sm1 * invs;
    feat[bs * 512 + 256 + d] = mx2;
    feat[bs * 512 + 384 + d] = sm2 * invs;
}

// ---------------------------------------------------------------------------
// MLP head: y1raw = bias; then split-K GEMM with fp32 atomic accumulation
// ---------------------------------------------------------------------------
__global__ void init_y1(const float* __restrict__ bf1, float* __restrict__ y1raw) {
    int i = blockIdx.x * 256 + threadIdx.x;
    y1raw[i] = bf1[i & 511];
}

#define MLP1_KCH 96
__global__ __launch_bounds__(256) void mlp1_splitk(const float* __restrict__ feat,
                                                   const float* __restrict__ wf1,
                                                   float* __restrict__ y1raw) {
    __shared__ float fl[64][MLP1_KCH];
    int k0 = blockIdx.y * MLP1_KCH;
    int tid = threadIdx.x;
    for (int c = tid; c < 64 * MLP1_KCH; c += 256) {
        int row = c / MLP1_KCH;
        int kk = c - row * MLP1_KCH;
        fl[row][kk] = feat[(size_t)row * 6144 + k0 + kk];
    }
    __syncthreads();
    int col = blockIdx.x * 128 + (tid & 127);
    int rbase = (tid >> 7) * 32;
    float acc[32];
#pragma unroll
    for (int r = 0; r < 32; r++) acc[r] = 0.f;
    for (int kg = 0; kg < MLP1_KCH; kg += 4) {
        float w0 = wf1[(size_t)(k0 + kg + 0) * 512 + col];
        float w1 = wf1[(size_t)(k0 + kg + 1) * 512 + col];
        float w2 = wf1[(size_t)(k0 + kg + 2) * 512 + col];
        float w3 = wf1[(size_t)(k0 + kg + 3) * 512 + col];
#pragma unroll
        for (int r = 0; r < 32; r++) {
            float4 f = *(const float4*)&fl[rbase + r][kg];
            acc[r] += f.x * w0 + f.y * w1 + f.z * w2 + f.w * w3;
        }
    }
#pragma unroll
    for (int r = 0; r < 32; r++)
        atomicAdd(&y1raw[(size_t)(rbase + r) * 512 + col], acc[r]);
}

__global__ void bn_silu(const float* __restrict__ raw, const float* __restrict__ g,
                        const float* __restrict__ be, float* __restrict__ out, int C) {
    int j = blockIdx.x;
    int b = threadIdx.x;
    float v = raw[b * C + j];
    float h = v / (1.0f + __expf(-v));
    float s = h, s2 = h * h;
    for (int off = 1; off < 64; off <<= 1) {
        s += __shfl_xor(s, off);
        s2 += __shfl_xor(s2, off);
    }
    float mu = s * (1.0f / 64.0f);
    float var = s2 * (1.0f / 64.0f) - mu * mu;
    float scale = rsqrtf(var + 1e-5f) * g[j];
    out[b * C + j] = (h - mu) * scale + be[j];
}

__global__ void mlp2(const float* __restrict__ y1, const float* __restrict__ wf2,
                     const float* __restrict__ bf2, float* __restrict__ y2raw) {
    int j = blockIdx.x;
    int b = threadIdx.x;
    float acc = bf2[j];
    for (int k = 0; k < 512; k++) acc += y1[b * 512 + k] * wf2[k * 32 + j];
    y2raw[b * 32 + j] = acc;
}

__global__ void mlp3(const float* __restrict__ y2, const float* __restrict__ wf3,
                     const float* __restrict__ bf3, float* __restrict__ out) {
    int b = threadIdx.x;
    float l0 = bf3[0], l1 = bf3[1];
    for (int k = 0; k < 32; k++) {
        float v = y2[b * 32 + k];
        l0 += v * wf3[k * 2 + 0];
        l1 += v * wf3[k * 2 + 1];
    }
    float m = fmaxf(l0, l1);
    float e0 = __expf(l0 - m), e1 = __expf(l1 - m);
    float inv = 1.0f / (e0 + e1);
    out[b * 2 + 0] = e0 * inv;
    out[b * 2 + 1] = e1 * inv;
}

// ---------------------------------------------------------------------------
extern "C" void kernel_launch(void* const* d_in, const int* in_sizes, int n_in,
                              void* d_out, int out_size, void* d_ws, size_t ws_size,
                              hipStream_t stream) {
    const float* x   = (const float*)d_in[0];
    const int*   ei  = (const int*)d_in[1];
    const float* w1  = (const float*)d_in[2];
    const float* b1  = (const float*)d_in[3];
    const float* w2  = (const float*)d_in[4];
    const float* b2  = (const float*)d_in[5];
    const float* pe  = (const float*)d_in[6];
    const float* wf1 = (const float*)d_in[7];
    const float* bf1 = (const float*)d_in[8];
    const float* g1  = (const float*)d_in[9];
    const float* be1 = (const float*)d_in[10];
    const float* wf2 = (const float*)d_in[11];
    const float* bf2 = (const float*)d_in[12];
    const float* g2  = (const float*)d_in[13];
    const float* be2 = (const float*)d_in[14];
    const float* wf3 = (const float*)d_in[15];
    const float* bf3 = (const float*)d_in[16];
    float* out = (float*)d_out;

    const int* srcp = ei;
    const int* dstp = ei + NEDGE;

    // workspace layout
    float* ws = (float*)d_ws;
    size_t off = 0;
    float* agg1 = ws + off; off += (size_t)N_NODES * DIN;
    float* agg2 = ws + off; off += (size_t)N_NODES * DH;
    float* h1   = ws + off; off += (size_t)N_NODES * DH;
    bf16_t* h2bf = (bf16_t*)(ws + off); off += (size_t)N_NODES * DH / 2;
    bf16_t* h2T  = (bf16_t*)(ws + off); off += (size_t)N_NODES * DH / 2;
    float* y1raw = ws + off; off += 64 * 512;
    float* y1    = ws + off; off += 64 * 512;
    float* y2raw = ws + off; off += 64 * 32;
    float* y2    = ws + off; off += 64 * 32;
    int* deg  = (int*)(ws + off);
    int* offs = deg + N_NODES;
    int* eidx = offs + N_NODES + 1;
    float* ctxb = agg2;
    float* feat = agg1;

    // build CSR
    hipMemsetAsync(deg, 0, (size_t)N_NODES * sizeof(int), stream);
    count_deg<<<(NEDGE + 255) / 256, 256, 0, stream>>>(dstp, deg);
    scan_deg<<<1, 1024, 0, stream>>>(deg, offs);
    hipMemcpyAsync(deg, offs, (size_t)N_NODES * sizeof(int),
                   hipMemcpyDeviceToDevice, stream);
    fill_csr<<<(NEDGE + 255) / 256, 256, 0, stream>>>(srcp, dstp, deg, eidx);

    gather84<<<N_NODES / 4, 256, 0, stream>>>(x, offs, eidx, agg1);
    linear1<<<N_NODES / 8, 128, 0, stream>>>(x, agg1, w1, b1, h1);
    gather128<<<N_NODES / 2, 256, 0, stream>>>(h1, offs, eidx, agg2);
    linear2<<<N_NODES / 8, 128, 0, stream>>>(h1, agg2, w2, b2, pe, h2bf);
    transposeK<<<dim3(32, 4, BG), dim3(32, 8), 0, stream>>>(h2bf, h2T);
    attn_mfma<<<BG * 16, 256, 0, stream>>>(h2bf, h2T, ctxb);
    pooling<<<BG * NSNAP, 128, 0, stream>>>(h1, ctxb, feat);
    init_y1<<<128, 256, 0, stream>>>(bf1, y1raw);
    mlp1_splitk<<<dim3(4, 64), 256, 0, stream>>>(feat, wf1, y1raw);
    bn_silu<<<512, 64, 0, stream>>>(y1raw, g1, be1, y1, 512);
    mlp2<<<32, 64, 0, stream>>>(y1, wf2, bf2, y2raw);
    bn_silu<<<32, 64, 0, stream>>>(y2raw, g2, be2, y2, 32);
    mlp3<<<1, 64, 0, stream>>>(y2, wf3, bf3, out);
}